// Round 6
// baseline (551.373 us; speedup 1.0000x reference)
//
#include <hip/hip_runtime.h>
#include <cmath>

// ---------------------------------------------------------------------------
// Gemma4 audio attention, MI355X bf16-MFMA pipeline.
// B=2 S=8192 HID=1024 H=8 D=128 CHUNK=128 PAST=127 FUT=128 CTX=383 POS=384
// R11: attn_k wave remap (the one change this round): 4 waves = (rh,kh) =
//      32 rows x 64 keys each (was 16 rows x 128 keys). Each K/V LDS fragment
//      feeds TWO row-group MFMAs -> per-CU LDS-read issue halves (the
//      dominant cost term). PV is key-partial; cross-pair reduction through
//      the freed Ks slab at the end. bd preload reverted (proven null).
//      Everything else byte-identical to R10.
// ---------------------------------------------------------------------------

using bf16x8 = __attribute__((ext_vector_type(8))) short;
using f32x4  = __attribute__((ext_vector_type(4))) float;
using s16x4  = __attribute__((ext_vector_type(4))) short;

__device__ __forceinline__ short f2bf(float f) {
  unsigned u = __float_as_uint(f);
  u = (u + 0x7FFF + ((u >> 16) & 1)) >> 16;   // RNE
  return (short)u;
}
__device__ __forceinline__ float bf2f(unsigned short s) {
  return __uint_as_float(((unsigned)s) << 16);
}

// async global->LDS, 16B per lane. LDS dest must be wave-uniform base + lane*16.
__device__ __forceinline__ void gl16(void* lds, const void* gptr) {
  __builtin_amdgcn_global_load_lds(
      (const __attribute__((address_space(1))) unsigned int*)gptr,
      (__attribute__((address_space(3))) unsigned int*)lds, 16, 0, 0);
}

// ---------------------------------------------------------------------------
// elementwise fp32 -> bf16
__global__ void cvt_bf16_k(const float* __restrict__ in, short* __restrict__ out, int n) {
  int i = (blockIdx.x * 256 + threadIdx.x) * 4;
  if (i + 3 < n) {
    float4 v = *(const float4*)&in[i];
    s16x4 o;
    o[0] = f2bf(v.x); o[1] = f2bf(v.y); o[2] = f2bf(v.z); o[3] = f2bf(v.w);
    *(s16x4*)&out[i] = o;
  }
}

// All 5 weights (1024x1024 f32, [k][n]) -> Wt (bf16, [n][k]), one launch.
__global__ void wtrans5_k(const float* __restrict__ W0, const float* __restrict__ W1,
                          const float* __restrict__ W2, const float* __restrict__ W3,
                          const float* __restrict__ W4, short* __restrict__ Wt_all) {
  __shared__ float T[64 * 65];
  const int tid = threadIdx.x;
  const int bx = blockIdx.x, by = blockIdx.y; // bx: n-tile, by: k-tile
  const int z = blockIdx.z;
  const float* W = W0;
  if (z == 1) W = W1;
  else if (z == 2) W = W2;
  else if (z == 3) W = W3;
  else if (z == 4) W = W4;
  short* Wt = Wt_all + (size_t)z * 1024 * 1024;
#pragma unroll
  for (int it = 0; it < 4; ++it) {
    int ci = it * 256 + tid;
    int k = ci >> 4, n4 = (ci & 15) * 4;
    float4 v = *(const float4*)&W[(size_t)(by * 64 + k) * 1024 + bx * 64 + n4];
    T[k * 65 + n4 + 0] = v.x;
    T[k * 65 + n4 + 1] = v.y;
    T[k * 65 + n4 + 2] = v.z;
    T[k * 65 + n4 + 3] = v.w;
  }
  __syncthreads();
#pragma unroll
  for (int it = 0; it < 2; ++it) {
    int co = it * 256 + tid;
    int nn = co >> 3, k8 = (co & 7) * 8;
    bf16x8 o;
#pragma unroll
    for (int jj = 0; jj < 8; ++jj) o[jj] = f2bf(T[(k8 + jj) * 65 + nn]);
    *(bf16x8*)&Wt[(size_t)(bx * 64 + nn) * 1024 + by * 64 + k8] = o;
  }
}

// qscale[d] = (1/sqrt(128))/ln2 * softplus(pds[d])
__global__ void qscale_k(const float* __restrict__ pds, float* __restrict__ qs, double qsb) {
  int d = threadIdx.x;
  double x = (double)pds[d];
  qs[d] = (float)(qsb * log1p(exp(x)));
}

// zero vpadT pad columns: keys [0,127) and [8319,8448)
__global__ void vpadzero_k(short* __restrict__ vpadT) {
  int row = blockIdx.x;                 // (b*8+h)*128 + d   (2048 rows)
  int t = threadIdx.x;                  // 256
  int key = (t < 127) ? t : (8192 + t); // 0..126 and 8319..8447
  vpadT[(size_t)row * 8448 + key] = 0;
}

// zero kpad pad rows only: keys [0,127) and [8319,8448).
__global__ void kpadzero_k(short* __restrict__ kpad) {
  int bx = blockIdx.x;                  // 0..255 pad-row index
  int bh = blockIdx.y;                  // b*8+h, 0..15
  int key = (bx < 127) ? bx : (8192 + bx);
  kpad[((size_t)bh * 8448 + key) * 128 + threadIdx.x] = 0;
}

// ---------------------------------------------------------------------------
// 256x256/8-phase GEMM building blocks.
__device__ __forceinline__ void stage_half(short* ldsb, const short* gbase, int tid) {
#pragma unroll
  for (int it = 0; it < 2; ++it) {
    int idx = it * 512 + tid;          // 16B-unit index, 0..1023
    int r = idx >> 3;                  // row 0..127
    int slot = idx & 7;
    int src = (slot ^ (r & 7)) << 3;   // short offset within the row
    gl16((char*)ldsb + idx * 16, gbase + (size_t)r * 1024 + src);
  }
}

__device__ __forceinline__ bf16x8 frag_ld(const short* hb, int row, int ks, int q4) {
  int slot = (ks * 4 + q4) ^ (row & 7);
  return *(const bf16x8*)((const char*)hb + row * 128 + slot * 16);
}

// ---------------------------------------------------------------------------
// Fused QKV GEMM: 256x256 tile, BK=64, 8-phase pipeline (unchanged).
__global__ __launch_bounds__(512, 2)
void qkv256_k(const short* __restrict__ A, const short* __restrict__ Bt3,
              short* __restrict__ q_bf, short* __restrict__ kpad,
              short* __restrict__ vpadT,
              const float* __restrict__ qsc, float kscale) {
  __shared__ __align__(16) short lds[65536];

  const int tid = threadIdx.x;
  const int lane = tid & 63, wid = tid >> 6;
  const int q4 = lane >> 4, l16 = lane & 15;
  const int wr = wid >> 2, wc = wid & 3;          // 2 M-waves x 4 N-waves

  const int id = blockIdx.x;
  const int xcd = id & 7, local = id >> 3;
  const int mm = xcd * 8 + local / 12, nn = local % 12;
  const int m0 = mm * 256, n0 = nn * 256;

  const short* Abase = A + (size_t)m0 * 1024;     // row-major [16384][1024]
  const short* Bbase = Bt3 + (size_t)n0 * 1024;   // 3 weights contiguous, [n][k]

  const f32x4 z4 = {0.f, 0.f, 0.f, 0.f};
  f32x4 acc[8][4];
#pragma unroll
  for (int i = 0; i < 8; ++i)
#pragma unroll
    for (int j = 0; j < 4; ++j) acc[i][j] = z4;

  stage_half(lds + 0 * 32768 + 0 * 8192, Abase, tid);
  stage_half(lds + 0 * 32768 + 1 * 8192, Abase + 128 * 1024, tid);
  stage_half(lds + 0 * 32768 + 2 * 8192, Bbase, tid);
  stage_half(lds + 0 * 32768 + 3 * 8192, Bbase + 128 * 1024, tid);
  stage_half(lds + 1 * 32768 + 2 * 8192, Bbase + 64, tid);
  stage_half(lds + 1 * 32768 + 3 * 8192, Bbase + 128 * 1024 + 64, tid);
  asm volatile("s_waitcnt vmcnt(4)" ::: "memory");
  __builtin_amdgcn_s_barrier();

  for (int kt = 0; kt < 16; ++kt) {
    const int buf = kt & 1;
    const short* Acur = lds + buf * 32768 + wr * 8192;
    const short* Bcur = lds + buf * 32768 + (2 + (wc >> 1)) * 8192;
    const int brow0 = (wc & 1) * 64;

    bf16x8 bfr[4][2];

    {
#pragma unroll
      for (int j = 0; j < 4; ++j)
#pragma unroll
        for (int ks = 0; ks < 2; ++ks)
          bfr[j][ks] = frag_ld(Bcur, brow0 + j * 16 + l16, ks, q4);
      bf16x8 afr[2][2];
#pragma unroll
      for (int m2 = 0; m2 < 2; ++m2)
#pragma unroll
        for (int ks = 0; ks < 2; ++ks)
          afr[m2][ks] = frag_ld(Acur, m2 * 16 + l16, ks, q4);
      if (kt < 15)
        stage_half(lds + (buf ^ 1) * 32768 + 0 * 8192, Abase + (size_t)(kt + 1) * 64, tid);
      asm volatile("s_waitcnt lgkmcnt(8)" ::: "memory");
      __builtin_amdgcn_s_barrier();
      asm volatile("s_waitcnt lgkmcnt(0)" ::: "memory");
      __builtin_amdgcn_s_setprio(1);
#pragma unroll
      for (int ks = 0; ks < 2; ++ks)
#pragma unroll
        for (int m2 = 0; m2 < 2; ++m2)
#pragma unroll
          for (int j = 0; j < 4; ++j)
            acc[m2][j] = __builtin_amdgcn_mfma_f32_16x16x32_bf16(
                afr[m2][ks], bfr[j][ks], acc[m2][j], 0, 0, 0);
      __builtin_amdgcn_s_setprio(0);
      __builtin_amdgcn_s_barrier();
    }

#pragma unroll
    for (int p = 1; p < 4; ++p) {
      bf16x8 afr[2][2];
#pragma unroll
      for (int m2 = 0; m2 < 2; ++m2)
#pragma unroll
        for (int ks = 0; ks < 2; ++ks)
          afr[m2][ks] = frag_ld(Acur, (p * 2 + m2) * 16 + l16, ks, q4);
      if (p == 1) {
        if (kt < 15)
          stage_half(lds + (buf ^ 1) * 32768 + 1 * 8192,
                     Abase + 128 * 1024 + (size_t)(kt + 1) * 64, tid);
      } else if (p == 2) {
        if (kt < 14)
          stage_half(lds + buf * 32768 + 2 * 8192, Bbase + (size_t)(kt + 2) * 64, tid);
      } else {
        if (kt < 14)
          stage_half(lds + buf * 32768 + 3 * 8192,
                     Bbase + 128 * 1024 + (size_t)(kt + 2) * 64, tid);
      }
      __builtin_amdgcn_s_barrier();
      asm volatile("s_waitcnt lgkmcnt(0)" ::: "memory");
      __builtin_amdgcn_s_setprio(1);
#pragma unroll
      for (int ks = 0; ks < 2; ++ks)
#pragma unroll
        for (int m2 = 0; m2 < 2; ++m2)
#pragma unroll
          for (int j = 0; j < 4; ++j)
            acc[p * 2 + m2][j] = __builtin_amdgcn_mfma_f32_16x16x32_bf16(
                afr[m2][ks], bfr[j][ks], acc[p * 2 + m2][j], 0, 0, 0);
      __builtin_amdgcn_s_setprio(0);
      if (p == 3) {
        if (kt < 14) asm volatile("s_waitcnt vmcnt(4)" ::: "memory");
        else         asm volatile("s_waitcnt vmcnt(0)" ::: "memory");
      }
      __builtin_amdgcn_s_barrier();
    }
  }

  const int w = n0 >> 10;          // 0=Q,1=K,2=V
  const int cw = n0 & 1023;
  const int b = m0 >> 13;
  const int s_base = (m0 & 8191) + wr * 128;

  if (w == 0) {
    float qsv[4];
#pragma unroll
    for (int j = 0; j < 4; ++j) qsv[j] = qsc[(cw + wc * 64 + j * 16 + l16) & 127];
#pragma unroll
    for (int m = 0; m < 8; ++m)
#pragma unroll
      for (int j = 0; j < 4; ++j)
#pragma unroll
        for (int rg = 0; rg < 4; ++rg) {
          int s = s_base + m * 16 + q4 * 4 + rg;
          int col = cw + wc * 64 + j * 16 + l16;
          int h = col >> 7, d = col & 127;
          int n = s >> 7, c = s & 127;
          q_bf[((size_t)(((b * 64 + n) * 8 + h) * 128 + c)) * 128 + d] =
              f2bf(acc[m][j][rg] * qsv[j]);
        }
  } else if (w == 1) {
#pragma unroll
    for (int m = 0; m < 8; ++m)
#pragma unroll
      for (int j = 0; j < 4; ++j)
#pragma unroll
        for (int rg = 0; rg < 4; ++rg) {
          int s = s_base + m * 16 + q4 * 4 + rg;
          int col = cw + wc * 64 + j * 16 + l16;
          int h = col >> 7, d = col & 127;
          kpad[((size_t)(b * 8 + h) * 8448 + 127 + s) * 128 + d] =
              f2bf(acc[m][j][rg] * kscale);
        }
  } else {
    short* T = lds;
#pragma unroll
    for (int hh = 0; hh < 2; ++hh) {
      __syncthreads();
      if ((wc >> 1) == hh) {
#pragma unroll
        for (int m = 0; m < 8; ++m)
#pragma unroll
          for (int j = 0; j < 4; ++j)
#pragma unroll
            for (int rg = 0; rg < 4; ++rg) {
              int sl = wr * 128 + m * 16 + q4 * 4 + rg;
              int dl = (wc & 1) * 64 + j * 16 + l16;
              T[dl * 264 + sl] = f2bf(acc[m][j][rg]);
            }
      }
      __syncthreads();
      const int h = (cw >> 7) + hh;
#pragma unroll
      for (int it = 0; it < 8; ++it) {
        int co = it * 512 + tid;
        int dd = co >> 5, s8 = (co & 31) * 8;
        *(bf16x8*)&vpadT[((size_t)(b * 8 + h) * 128 + dd) * 8448 + 127 + (m0 & 8191) + s8] =
            *(const bf16x8*)&T[dd * 264 + s8];
      }
    }
  }
}

// ---------------------------------------------------------------------------
// Post GEMM on the 256x256/8-phase template (unchanged).
__global__ __launch_bounds__(512, 2)
void post256_k(const short* __restrict__ A, const short* __restrict__ Bt,
               float* __restrict__ outf) {
  __shared__ __align__(16) short lds[65536];

  const int tid = threadIdx.x;
  const int lane = tid & 63, wid = tid >> 6;
  const int q4 = lane >> 4, l16 = lane & 15;
  const int wr = wid >> 2, wc = wid & 3;

  const int id = blockIdx.x;
  const int xcd = id & 7, local = id >> 3;      // local in [0,32)
  const int mm = xcd * 8 + (local >> 2), nn = local & 3;
  const int m0 = mm * 256, n0 = nn * 256;

  const short* Abase = A + (size_t)m0 * 1024;
  const short* Bbase = Bt + (size_t)n0 * 1024;

  const f32x4 z4 = {0.f, 0.f, 0.f, 0.f};
  f32x4 acc[8][4];
#pragma unroll
  for (int i = 0; i < 8; ++i)
#pragma unroll
    for (int j = 0; j < 4; ++j) acc[i][j] = z4;

  stage_half(lds + 0 * 32768 + 0 * 8192, Abase, tid);
  stage_half(lds + 0 * 32768 + 1 * 8192, Abase + 128 * 1024, tid);
  stage_half(lds + 0 * 32768 + 2 * 8192, Bbase, tid);
  stage_half(lds + 0 * 32768 + 3 * 8192, Bbase + 128 * 1024, tid);
  stage_half(lds + 1 * 32768 + 2 * 8192, Bbase + 64, tid);
  stage_half(lds + 1 * 32768 + 3 * 8192, Bbase + 128 * 1024 + 64, tid);
  asm volatile("s_waitcnt vmcnt(4)" ::: "memory");
  __builtin_amdgcn_s_barrier();

  for (int kt = 0; kt < 16; ++kt) {
    const int buf = kt & 1;
    const short* Acur = lds + buf * 32768 + wr * 8192;
    const short* Bcur = lds + buf * 32768 + (2 + (wc >> 1)) * 8192;
    const int brow0 = (wc & 1) * 64;

    bf16x8 bfr[4][2];

    {
#pragma unroll
      for (int j = 0; j < 4; ++j)
#pragma unroll
        for (int ks = 0; ks < 2; ++ks)
          bfr[j][ks] = frag_ld(Bcur, brow0 + j * 16 + l16, ks, q4);
      bf16x8 afr[2][2];
#pragma unroll
      for (int m2 = 0; m2 < 2; ++m2)
#pragma unroll
        for (int ks = 0; ks < 2; ++ks)
          afr[m2][ks] = frag_ld(Acur, m2 * 16 + l16, ks, q4);
      if (kt < 15)
        stage_half(lds + (buf ^ 1) * 32768 + 0 * 8192, Abase + (size_t)(kt + 1) * 64, tid);
      asm volatile("s_waitcnt lgkmcnt(8)" ::: "memory");
      __builtin_amdgcn_s_barrier();
      asm volatile("s_waitcnt lgkmcnt(0)" ::: "memory");
      __builtin_amdgcn_s_setprio(1);
#pragma unroll
      for (int ks = 0; ks < 2; ++ks)
#pragma unroll
        for (int m2 = 0; m2 < 2; ++m2)
#pragma unroll
          for (int j = 0; j < 4; ++j)
            acc[m2][j] = __builtin_amdgcn_mfma_f32_16x16x32_bf16(
                afr[m2][ks], bfr[j][ks], acc[m2][j], 0, 0, 0);
      __builtin_amdgcn_s_setprio(0);
      __builtin_amdgcn_s_barrier();
    }

#pragma unroll
    for (int p = 1; p < 4; ++p) {
      bf16x8 afr[2][2];
#pragma unroll
      for (int m2 = 0; m2 < 2; ++m2)
#pragma unroll
        for (int ks = 0; ks < 2; ++ks)
          afr[m2][ks] = frag_ld(Acur, (p * 2 + m2) * 16 + l16, ks, q4);
      if (p == 1) {
        if (kt < 15)
          stage_half(lds + (buf ^ 1) * 32768 + 1 * 8192,
                     Abase + 128 * 1024 + (size_t)(kt + 1) * 64, tid);
      } else if (p == 2) {
        if (kt < 14)
          stage_half(lds + buf * 32768 + 2 * 8192, Bbase + (size_t)(kt + 2) * 64, tid);
      } else {
        if (kt < 14)
          stage_half(lds + buf * 32768 + 3 * 8192,
                     Bbase + 128 * 1024 + (size_t)(kt + 2) * 64, tid);
      }
      __builtin_amdgcn_s_barrier();
      asm volatile("s_waitcnt lgkmcnt(0)" ::: "memory");
      __builtin_amdgcn_s_setprio(1);
#pragma unroll
      for (int ks = 0; ks < 2; ++ks)
#pragma unroll
        for (int m2 = 0; m2 < 2; ++m2)
#pragma unroll
          for (int j = 0; j < 4; ++j)
            acc[p * 2 + m2][j] = __builtin_amdgcn_mfma_f32_16x16x32_bf16(
                afr[m2][ks], bfr[j][ks], acc[p * 2 + m2][j], 0, 0, 0);
      __builtin_amdgcn_s_setprio(0);
      if (p == 3) {
        if (kt < 14) asm volatile("s_waitcnt vmcnt(4)" ::: "memory");
        else         asm volatile("s_waitcnt vmcnt(0)" ::: "memory");
      }
      __builtin_amdgcn_s_barrier();
    }
  }

#pragma unroll
  for (int m = 0; m < 8; ++m)
#pragma unroll
    for (int j = 0; j < 4; ++j)
#pragma unroll
      for (int rg = 0; rg < 4; ++rg) {
        const int row = m0 + wr * 128 + m * 16 + q4 * 4 + rg;
        const int col = n0 + wc * 64 + j * 16 + l16;
        outf[(size_t)row * 1024 + col] = acc[m][j][rg];
      }
}

// ---------------------------------------------------------------------------
// REL GEMM (counted-vmcnt double-buffer, unchanged from R10).
__global__ __launch_bounds__(256, 2)
void rel_gemm_k(const short* __restrict__ A, const short* __restrict__ Bt,
                short* __restrict__ relk) {
  __shared__ __align__(16) short As[2][128 * 32];
  __shared__ __align__(16) short Bs[2][128 * 32];

  const int tid = threadIdx.x;
  const int lane = tid & 63, wid = tid >> 6;
  const int q4 = lane >> 4, l16 = lane & 15;
  const int wr = wid >> 1, wc = wid & 1;
  const int m0 = blockIdx.x * 128, n0 = blockIdx.y * 128;

  const f32x4 z4 = {0.f, 0.f, 0.f, 0.f};
  f32x4 acc[4][4];
#pragma unroll
  for (int i = 0; i < 4; ++i)
#pragma unroll
    for (int j = 0; j < 4; ++j) acc[i][j] = z4;

  const int r0 = tid >> 2, s0_ = (tid & 3) * 8;

  {
    gl16(&As[0][tid * 8],         A  + (size_t)(m0 + r0) * 1024 + s0_);
    gl16(&Bs[0][tid * 8],         Bt + (size_t)(n0 + r0) * 1024 + s0_);
    gl16(&As[0][(256 + tid) * 8], A  + (size_t)(m0 + 64 + r0) * 1024 + s0_);
    gl16(&Bs[0][(256 + tid) * 8], Bt + (size_t)(n0 + 64 + r0) * 1024 + s0_);
  }

  for (int kt = 0; kt < 32; ++kt) {
    const int buf = kt & 1;
    if (kt < 31) {
      const int kk = (kt + 1) * 32;
      gl16(&As[buf ^ 1][tid * 8],         A  + (size_t)(m0 + r0) * 1024 + kk + s0_);
      gl16(&Bs[buf ^ 1][tid * 8],         Bt + (size_t)(n0 + r0) * 1024 + kk + s0_);
      gl16(&As[buf ^ 1][(256 + tid) * 8], A  + (size_t)(m0 + 64 + r0) * 1024 + kk + s0_);
      gl16(&Bs[buf ^ 1][(256 + tid) * 8], Bt + (size_t)(n0 + 64 + r0) * 1024 + kk + s0_);
      asm volatile("s_waitcnt vmcnt(4)" ::: "memory");
    } else {
      asm volatile("s_waitcnt vmcnt(0)" ::: "memory");
    }
    __builtin_amdgcn_s_barrier();

    bf16x8 af[4], bfv[4];
#pragma unroll
    for (int i = 0; i < 4; ++i)
      af[i] = *(const bf16x8*)&As[buf][(wr * 64 + i * 16 + l16) * 32 + q4 * 8];
#pragma unroll
    for (int j = 0; j < 4; ++j)
      bfv[j] = *(const bf16x8*)&Bs[buf][(wc * 64 + j * 16 + l16) * 32 + q4 * 8];
#pragma unroll
    for (int i = 0; i < 4; ++i)
#pragma unroll
      for (int j = 0; j < 4; ++j)
        acc[i][j] = __builtin_amdgcn_mfma_f32_16x16x32_bf16(af[i], bfv[j], acc[i][j], 0, 0, 0);
    __builtin_amdgcn_s_barrier();
  }

#pragma unroll
  for (int i = 0; i < 4; ++i)
#pragma unroll
    for (int j = 0; j < 4; ++j)
#pragma unroll
      for (int rg = 0; rg < 4; ++rg) {
        const int row = m0 + wr * 64 + i * 16 + q4 * 4 + rg;
        const int col = n0 + wc * 64 + j * 16 + l16;
        int h = col >> 7, d = col & 127;
        relk[(size_t)(h * 384 + row) * 128 + d] = f2bf(acc[i][j][rg]);
      }
}

// ---------------------------------------------------------------------------
// bdo = q_tile(128x128) @ relk[h](384x128)^T, rel-shift in epilogue (unchanged).
__global__ __launch_bounds__(256, 2)
void bd_gemm_k(const short* __restrict__ qb_b, const short* __restrict__ relk,
               short* __restrict__ bds) {
  __shared__ __align__(16) short As[128 * 32];
  __shared__ __align__(16) short Bs[128 * 32];
  const int tid = threadIdx.x;
  const int lane = tid & 63, wid = tid >> 6;
  const int q4 = lane >> 4, l16 = lane & 15;
  const int wr = wid >> 1, wc = wid & 1;
  const int p0 = blockIdx.x * 128;
  const int nh = blockIdx.y;          // n*8 + h  (within b)
  const int h = nh & 7;
  const short* A = qb_b + (size_t)nh * 16384;
  const short* Bt = relk + (size_t)h * (384 * 128);
  short* bdo = bds + (size_t)nh * 49152;

  const f32x4 z4 = {0.f, 0.f, 0.f, 0.f};
  f32x4 acc[4][4];
#pragma unroll
  for (int i = 0; i < 4; ++i)
#pragma unroll
    for (int j = 0; j < 4; ++j) acc[i][j] = z4;

  const int r0 = tid >> 2, s0_ = (tid & 3) * 8;
  for (int kk = 0; kk < 128; kk += 32) {
    __syncthreads();
    gl16(&As[tid * 8],         A  + (size_t)r0 * 128 + kk + s0_);
    gl16(&Bs[tid * 8],         Bt + (size_t)(p0 + r0) * 128 + kk + s0_);
    gl16(&As[(256 + tid) * 8], A  + (size_t)(64 + r0) * 128 + kk + s0_);
    gl16(&Bs[(256 + tid) * 8], Bt + (size_t)(p0 + 64 + r0) * 128 + kk + s0_);
    __syncthreads();
    bf16x8 af[4], bfv[4];
#pragma unroll
    for (int i = 0; i < 4; ++i)
      af[i] = *(const bf16x8*)&As[(wr * 64 + i * 16 + l16) * 32 + q4 * 8];
#pragma unroll
    for (int j = 0; j < 4; ++j)
      bfv[j] = *(const bf16x8*)&Bs[(wc * 64 + j * 16 + l16) * 32 + q4 * 8];
#pragma unroll
    for (int i = 0; i < 4; ++i)
#pragma unroll
      for (int j = 0; j < 4; ++j)
        acc[i][j] = __builtin_amdgcn_mfma_f32_16x16x32_bf16(af[i], bfv[j], acc[i][j], 0, 0, 0);
  }

#pragma unroll
  for (int i = 0; i < 4; ++i)
#pragma unroll
    for (int j = 0; j < 4; ++j)
#pragma unroll
      for (int rg = 0; rg < 4; ++rg) {
        int r = wr * 64 + i * 16 + q4 * 4 + rg;
        int p = p0 + wc * 64 + j * 16 + l16;
        int t = r + p;
        int c = (t < 383) ? r : (r + 1);
        int k = (t < 383) ? t : (t - 383);
        if (c < 128) {
          int tt = k >> 7, jj = (k >> 4) & 7, ll = k & 15;
          int wa = c >> 5, ia = (c >> 4) & 1, qa = (c >> 2) & 3, ra = c & 3;
          bdo[((((size_t)tt * 8 + jj) * 256) + wa * 64 + qa * 16 + ll) * 8 + ia * 4 + ra] =
              f2bf(acc[i][j][rg]);
        }
      }
}

// ---------------------------------------------------------------------------
// R11 fused local attention: wave remap (rh,kh) = 32 rows x 64 keys per wave.
// Each kf/vf LDS fragment feeds TWO row-group MFMAs -> per-wave K/V LDS reads
// halve (32->16 b128 per tile each). PV is key-partial; cross-pair reduction
// through the freed Ks slab at the end. Counted-vmcnt schedule + XCD head
// pinning unchanged. LDS 80KB -> 2 blocks/CU.
__global__ __launch_bounds__(256, 2)
void attn_k(const short* __restrict__ qb_b, const short* __restrict__ kpad,
            const short* __restrict__ vpadT, const short* __restrict__ bds,
            short* __restrict__ attnout, int b) {
  __shared__ __align__(16) short Ks[4 * 128 * 32]; // K slabs [dc][key][32]; f32 scratch at end
  __shared__ __align__(16) short Vs[4 * 128 * 32]; // V slabs [kc][d][32keys]
  __shared__ __align__(16) short Ps[64 * 128];     // Q stage -> P tile (XOR); rsum scratch

  const int tid = threadIdx.x;
  const int lane = tid & 63, wid = tid >> 6;
  const int q4 = lane >> 4, l16 = lane & 15;
  const int rh = wid >> 1, kh = wid & 1;           // row-half, key-half
  const int bx = blockIdx.x;
  const int h = bx & 7;               // XCD-pinned head
  const int local = bx >> 3;          // [0,128)
  const int n = local >> 1, qh = local & 1;
  const int nh = n * 8 + h;

  const short* qtile = qb_b + (size_t)nh * 16384 + qh * 64 * 128;
  const short* kbase = kpad + ((size_t)(b * 8 + h) * 8448 + n * 128) * 128;
  const short* vtb = vpadT + (size_t)(b * 8 + h) * 128 * 8448 + n * 128;
  const short* bdb = bds + (size_t)nh * 49152;

  // ---- prologue: Q -> Ps, K(0) -> Ks; wait Q only (K stays in flight)
#pragma unroll
  for (int it = 0; it < 4; ++it) {
    int ci = it * 256 + tid;                     // [0,1024)
    int dc = ci >> 8, rr = (ci >> 2) & 63, sub = (ci & 3) * 8;
    gl16(&Ps[ci * 8], qtile + rr * 128 + dc * 32 + sub);
  }
  asm volatile("" ::: "memory");
#pragma unroll
  for (int it = 0; it < 8; ++it) {
    int ci = it * 256 + tid;
    int dc = ci >> 9, rr = (ci >> 2) & 127, sub = (ci & 3) * 8;
    gl16(&Ks[ci * 8], kbase + (size_t)rr * 128 + dc * 32 + sub);
  }
  asm volatile("s_waitcnt vmcnt(8)" ::: "memory");  // Q landed; K(0) outstanding
  asm volatile("s_barrier" ::: "memory");
  bf16x8 qf[2][4];                                  // rows rh*32+i*16+l16
#pragma unroll
  for (int i = 0; i < 2; ++i)
#pragma unroll
    for (int dc = 0; dc < 4; ++dc)
      qf[i][dc] = *(const bf16x8*)&Ps[dc * 2048 + (rh * 32 + i * 16 + l16) * 32 + q4 * 8];
  asm volatile("s_waitcnt lgkmcnt(0)" ::: "memory"); // Q reads retired

  const f32x4 z4 = {0.f, 0.f, 0.f, 0.f};
  f32x4 acco[2][8];
#pragma unroll
  for (int i = 0; i < 2; ++i)
#pragma unroll
    for (int j = 0; j < 8; ++j) acco[i][j] = z4;
  float rsum[2][4] = {};

#pragma unroll
  for (int t = 0; t < 3; ++t) {
    asm volatile("s_barrier" ::: "memory");  // (A) Vs/Ps free

    // bd fragment loads (ordered BEFORE V so vmcnt(8) covers them)
    s16x4 bdv[2][4];
#pragma unroll
    for (int i = 0; i < 2; ++i)
#pragma unroll
      for (int jl = 0; jl < 4; ++jl)
        bdv[i][jl] = *(const s16x4*)&bdb[(size_t)(t * 8 + kh * 4 + jl) * 2048 +
                       ((qh * 2 + rh) * 64 + q4 * 16 + l16) * 8 + i * 4];
    asm volatile("" ::: "memory");

    // stage V(t) -> Vs (waited only before PV)
#pragma unroll
    for (int it = 0; it < 8; ++it) {
      int ci = it * 256 + tid;
      int kc = ci >> 9, dd = (ci >> 2) & 127, sub = (ci & 3) * 8;
      gl16(&Vs[ci * 8], vtb + (size_t)dd * 8448 + t * 128 + kc * 32 + sub);
    }

    asm volatile("s_waitcnt vmcnt(8)" ::: "memory"); // K(t)+bdv done, V in flight
    asm volatile("s_barrier" ::: "memory");  // (B) K visible to all waves

    // S = Q @ K^T : 32 rows x 64 keys per wave (kf shared by both row-groups)
    f32x4 accs[2][4];
#pragma unroll
    for (int i = 0; i < 2; ++i)
#pragma unroll
      for (int jl = 0; jl < 4; ++jl) accs[i][jl] = z4;
    __builtin_amdgcn_s_setprio(1);
#pragma unroll
    for (int dc = 0; dc < 4; ++dc) {
      bf16x8 kf[4];
#pragma unroll
      for (int jl = 0; jl < 4; ++jl)
        kf[jl] = *(const bf16x8*)&Ks[dc * 4096 + ((kh * 4 + jl) * 16 + l16) * 32 + q4 * 8];
#pragma unroll
      for (int i = 0; i < 2; ++i)
#pragma unroll
        for (int jl = 0; jl < 4; ++jl)
          accs[i][jl] = __builtin_amdgcn_mfma_f32_16x16x32_bf16(
              qf[i][dc], kf[jl], accs[i][jl], 0, 0, 0);
    }
    __builtin_amdgcn_s_setprio(0);

    // logits
#pragma unroll
    for (int i = 0; i < 2; ++i)
#pragma unroll
      for (int jl = 0; jl < 4; ++jl) {
        const int kg = t * 128 + (kh * 4 + jl) * 16 + l16;
#pragma unroll
        for (int rg = 0; rg < 4; ++rg) {
          float sv = accs[i][jl][rg] + bf2f((unsigned short)bdv[i][jl][rg]);
          float tt = exp2f(sv * 0.057707801635558534f);
          float wgt = exp2f(-144.26950408889634f * __fdividef(1.0f, tt + 1.0f));
          wgt = (kg < 383) ? wgt : 0.0f;
          accs[i][jl][rg] = wgt;
          rsum[i][rg] += wgt;
        }
      }

    asm volatile("s_barrier" ::: "memory");  // (C) all waves done reading Ks

    // stage K(t+1) -> Ks
    if (t < 2) {
#pragma unroll
      for (int it = 0; it < 8; ++it) {
        int ci = it * 256 + tid;
        int dc = ci >> 9, rr = (ci >> 2) & 127, sub = (ci & 3) * 8;
        gl16(&Ks[ci * 8], kbase + (size_t)((t + 1) * 128 + rr) * 128 + dc * 32 + sub);
      }
    }

    // write P tile (granule-XOR layout), this wave's 32x64 quadrant
#pragma unroll
    for (int i = 0; i < 2; ++i)
#pragma unroll
      for (int jl = 0; jl < 4; ++jl)
#pragma unroll
        for (int rg = 0; rg < 4; ++rg) {
          int c = rh * 32 + i * 16 + q4 * 4 + rg;
          int kl = (kh * 4 + jl) * 16 + l16;
          int g = (kl >> 3) ^ (c & 7);
          Ps[c * 128 + g * 8 + (kl & 7)] = f2bf(accs[i][jl][rg]);
        }

    if (t < 2) asm volatile("s_waitcnt vmcnt(8)" ::: "memory"); // V(t) done, K(t+1) in flight
    else       asm volatile("s_waitcnt vmcnt(0)" ::: "memory");
    asm volatile("s_waitcnt lgkmcnt(0)" ::: "memory");          // P writes committed
    asm volatile("s_barrier" ::: "memory");  // (D) V + P ready

    // PV partial over this wave's 64 keys (vf shared by both row-groups)
    __builtin_amdgcn_s_setprio(1);
#pragma unroll
    for (int kcl = 0; kcl < 2; ++kcl) {
      const int kc = kh * 2 + kcl;
      bf16x8 pf[2];
#pragma unroll
      for (int i = 0; i < 2; ++i) {
        int c = rh * 32 + i * 16 + l16;
        int g = (kc * 4 + q4) ^ (c & 7);
        pf[i] = *(const bf16x8*)&Ps[c * 128 + g * 8];
      }
      bf16x8 vf[8];
#pragma unroll
      for (int j = 0; j < 8; ++j)
        vf[j] = *(const bf16x8*)&Vs[kc * 4096 + (j * 16 + l16) * 32 + q4 * 8];
#pragma unroll
      for (int i = 0; i < 2; ++i)
#pragma unroll
        for (int j = 0; j < 8; ++j)
          acco[i][j] = __builtin_amdgcn_mfma_f32_16x16x32_bf16(
              pf[i], vf[j], acco[i][j], 0, 0, 0);
    }
    __builtin_amdgcn_s_setprio(0);
  }

  // ---- cross key-half reduction + normalize + store -----------------------
  // butterfly rsum over the 16-lane col group (both kh)
#pragma unroll
  for (int i = 0; i < 2; ++i)
#pragma unroll
    for (int rg = 0; rg < 4; ++rg) {
      float rs = rsum[i][rg];
      rs += __shfl_xor(rs, 1);
      rs += __shfl_xor(rs, 2);
      rs += __shfl_xor(rs, 4);
      rs += __shfl_xor(rs, 8);
      rsum[i][rg] = rs;
    }

  __syncthreads();                      // PV done everywhere; Ks/Ps reusable
  float* scr = (float*)Ks;              // [64 rows][128 d] f32 = 32 KB
  float* psc = (float*)Ps;              // [64] f32 row sums
  if (kh == 1) {
#pragma unroll
    for (int i = 0; i < 2; ++i)
#pragma unroll
      for (int j = 0; j < 8; ++j)
#pragma unroll
        for (int rg = 0; rg < 4; ++rg) {
          int row = rh * 32 + i * 16 + q4 * 4 + rg;
          scr[row * 128 + j * 16 + l16] = acco[i][j][rg];
        }
    if (l16 == 0) {
#pragma unroll
      for (int i = 0; i < 2; ++i)
#pragma unroll
        for (int rg = 0; rg < 4; ++rg)
          psc[rh * 32 + i * 16 + q4 * 4 + rg] = rsum[i][rg];
    }
  }
  __syncthreads();
  if (kh == 0) {
    float rinv[2][4];
#pragma unroll
    for (int i = 0; i < 2; ++i)
#pragma unroll
      for (int rg = 0; rg < 4; ++rg) {
        int row = rh * 32 + i * 16 + q4 * 4 + rg;
        rinv[i][rg] = __fdividef(1.0f, rsum[i][rg] + psc[row]);
      }
#pragma unroll
    for (int i = 0; i < 2; ++i)
#pragma unroll
      for (int j = 0; j < 8; ++j)
#pragma unroll
        for (int rg = 0; rg < 4; ++rg) {
          int row = rh * 32 + i * 16 + q4 * 4 + rg;
          float osum = acco[i][j][rg] + scr[row * 128 + j * 16 + l16];
          int srow = n * 128 + qh * 64 + row;
          int col = h * 128 + j * 16 + l16;
          attnout[((size_t)b * 8192 + srow) * 1024 + col] = f2bf(osum * rinv[i][rg]);
        }
  }
}

// ---------------------------------------------------------------------------
extern "C" void kernel_launch(void* const* d_in, const int* in_sizes, int n_in,
                              void* d_out, int out_size, void* d_ws, size_t ws_size,
                              hipStream_t stream) {
  (void)in_sizes; (void)n_in; (void)out_size; (void)ws_size;
  const float* hs    = (const float*)d_in[0];
  const float* pemb  = (const float*)d_in[1];
  const float* Wq    = (const float*)d_in[2];
  const float* Wk    = (const float*)d_in[3];
  const float* Wv    = (const float*)d_in[4];
  const float* Wrel  = (const float*)d_in[5];
  const float* Wpost = (const float*)d_in[6];
  const float* pds   = (const float*)d_in[7];
  float* out = (float*)d_out;

  char* w = (char*)d_ws;
  auto alloc = [&](size_t bytes) -> char* {
    char* p = w; w += (bytes + 255) & ~(size_t)255; return p;
  };
  short* hs_bf   = (short*)alloc((size_t)16384 * 1024 * 2); // 33.5 MB (attnout aliases later)
  short* pos_bf  = (short*)alloc((size_t)384 * 1024 * 2);
  short* Wq_t    = (short*)alloc((size_t)1024 * 1024 * 2);  // Wq_t..Wpost_t contiguous
  short* Wk_t    = (short*)alloc((size_t)1024 * 1024 * 2);
  short* Wv_t    = (short*)alloc((size_t)1024 * 1024 * 2);
  short* Wrel_t  = (short*)alloc((size_t)1024 * 1024 * 2);
  short* Wpost_t = (short*)alloc((size_t)1024 * 1024 * 2);
  float* qsc     = (float*)alloc(512);
  short* q_bf    = (short*)alloc((size_t)2 * 64 * 8 * 128 * 128 * 2); // 33.5 MB
  short* kpad    = (short*)alloc((size_t)2 * 8 * 8448 * 128 * 2);     // 34.6 MB
  short* vpadT   = (short*)alloc((size_t)2 * 8 * 128 * 8448 * 2);     // 34.6 MB
  short* relk    = (short*)alloc((size_t)8 * 384 * 128 * 2);
  short* bds     = (short*)alloc((size_t)64 * 8 * 128 * 384 * 2);     // 50.3 MB, per-b (reused)
  short* attnout = hs_bf;  // hs_bf dead after QKV projection; attn starts after
  // total ~199 MB (< 232 MB known-good)

  const float kscale = (float)(log1p(exp(1.0)) / log(2.0));
  const double qsb = (1.0 / sqrt(128.0)) / log(2.0);

  cvt_bf16_k<<<16384, 256, 0, stream>>>(hs, hs_bf, 16384 * 1024);
  cvt_bf16_k<<<384, 256, 0, stream>>>(pemb, pos_bf, 384 * 1024);
  wtrans5_k<<<dim3(16, 16, 5), 256, 0, stream>>>(Wq, Wk, Wv, Wrel, Wpost, Wq_t);
  qscale_k<<<1, 128, 0, stream>>>(pds, qsc, qsb);
  kpadzero_k<<<dim3(256, 16), 128, 0, stream>>>(kpad);
  vpadzero_k<<<2048, 256, 0, stream>>>(vpadT);

  qkv256_k<<<768, 512, 0, stream>>>(hs_bf, Wq_t, q_bf, kpad, vpadT, qsc, kscale);
  rel_gemm_k<<<dim3(3, 8), 256, 0, stream>>>(pos_bf, Wrel_t, relk);

  for (int b = 0; b < 2; ++b) {
    const short* qb_b = q_bf + (size_t)b * 64 * 8 * 128 * 128;
    bd_gemm_k<<<dim3(3, 512), 256, 0, stream>>>(qb_b, relk, bds);
    attn_k<<<1024, 256, 0, stream>>>(qb_b, kpad, vpadT, bds, attnout, b);
  }

  post256_k<<<256, 512, 0, stream>>>(attnout, Wpost_t, out);
}

// Round 7
// 484.997 us; speedup vs baseline: 1.1369x; 1.1369x over previous
//
#include <hip/hip_runtime.h>
#include <cmath>

// ---------------------------------------------------------------------------
// Gemma4 audio attention, MI355X bf16-MFMA pipeline.
// B=2 S=8192 HID=1024 H=8 D=128 CHUNK=128 PAST=127 FUT=128 CTX=383 POS=384
// R12: (1) attn_k reverted to R10 exactly (R11 remap regressed: partial-PV
//      epilogue cost > halved LDS reads). (2) bd_gemm single-stage: K=128
//      staged to LDS once (64 KB), ONE drain + ONE barrier, then all 16
//      MFMA/wave with no intervening syncs (was 4 drains / 8 barriers).
//      Everything else byte-identical to R10.
// ---------------------------------------------------------------------------

using bf16x8 = __attribute__((ext_vector_type(8))) short;
using f32x4  = __attribute__((ext_vector_type(4))) float;
using s16x4  = __attribute__((ext_vector_type(4))) short;

__device__ __forceinline__ short f2bf(float f) {
  unsigned u = __float_as_uint(f);
  u = (u + 0x7FFF + ((u >> 16) & 1)) >> 16;   // RNE
  return (short)u;
}
__device__ __forceinline__ float bf2f(unsigned short s) {
  return __uint_as_float(((unsigned)s) << 16);
}

// async global->LDS, 16B per lane. LDS dest must be wave-uniform base + lane*16.
__device__ __forceinline__ void gl16(void* lds, const void* gptr) {
  __builtin_amdgcn_global_load_lds(
      (const __attribute__((address_space(1))) unsigned int*)gptr,
      (__attribute__((address_space(3))) unsigned int*)lds, 16, 0, 0);
}

// ---------------------------------------------------------------------------
// elementwise fp32 -> bf16
__global__ void cvt_bf16_k(const float* __restrict__ in, short* __restrict__ out, int n) {
  int i = (blockIdx.x * 256 + threadIdx.x) * 4;
  if (i + 3 < n) {
    float4 v = *(const float4*)&in[i];
    s16x4 o;
    o[0] = f2bf(v.x); o[1] = f2bf(v.y); o[2] = f2bf(v.z); o[3] = f2bf(v.w);
    *(s16x4*)&out[i] = o;
  }
}

// All 5 weights (1024x1024 f32, [k][n]) -> Wt (bf16, [n][k]), one launch.
__global__ void wtrans5_k(const float* __restrict__ W0, const float* __restrict__ W1,
                          const float* __restrict__ W2, const float* __restrict__ W3,
                          const float* __restrict__ W4, short* __restrict__ Wt_all) {
  __shared__ float T[64 * 65];
  const int tid = threadIdx.x;
  const int bx = blockIdx.x, by = blockIdx.y; // bx: n-tile, by: k-tile
  const int z = blockIdx.z;
  const float* W = W0;
  if (z == 1) W = W1;
  else if (z == 2) W = W2;
  else if (z == 3) W = W3;
  else if (z == 4) W = W4;
  short* Wt = Wt_all + (size_t)z * 1024 * 1024;
#pragma unroll
  for (int it = 0; it < 4; ++it) {
    int ci = it * 256 + tid;
    int k = ci >> 4, n4 = (ci & 15) * 4;
    float4 v = *(const float4*)&W[(size_t)(by * 64 + k) * 1024 + bx * 64 + n4];
    T[k * 65 + n4 + 0] = v.x;
    T[k * 65 + n4 + 1] = v.y;
    T[k * 65 + n4 + 2] = v.z;
    T[k * 65 + n4 + 3] = v.w;
  }
  __syncthreads();
#pragma unroll
  for (int it = 0; it < 2; ++it) {
    int co = it * 256 + tid;
    int nn = co >> 3, k8 = (co & 7) * 8;
    bf16x8 o;
#pragma unroll
    for (int jj = 0; jj < 8; ++jj) o[jj] = f2bf(T[(k8 + jj) * 65 + nn]);
    *(bf16x8*)&Wt[(size_t)(bx * 64 + nn) * 1024 + by * 64 + k8] = o;
  }
}

// qscale[d] = (1/sqrt(128))/ln2 * softplus(pds[d])
__global__ void qscale_k(const float* __restrict__ pds, float* __restrict__ qs, double qsb) {
  int d = threadIdx.x;
  double x = (double)pds[d];
  qs[d] = (float)(qsb * log1p(exp(x)));
}

// zero vpadT pad columns: keys [0,127) and [8319,8448)
__global__ void vpadzero_k(short* __restrict__ vpadT) {
  int row = blockIdx.x;                 // (b*8+h)*128 + d   (2048 rows)
  int t = threadIdx.x;                  // 256
  int key = (t < 127) ? t : (8192 + t); // 0..126 and 8319..8447
  vpadT[(size_t)row * 8448 + key] = 0;
}

// zero kpad pad rows only: keys [0,127) and [8319,8448).
__global__ void kpadzero_k(short* __restrict__ kpad) {
  int bx = blockIdx.x;                  // 0..255 pad-row index
  int bh = blockIdx.y;                  // b*8+h, 0..15
  int key = (bx < 127) ? bx : (8192 + bx);
  kpad[((size_t)bh * 8448 + key) * 128 + threadIdx.x] = 0;
}

// ---------------------------------------------------------------------------
// 256x256/8-phase GEMM building blocks.
__device__ __forceinline__ void stage_half(short* ldsb, const short* gbase, int tid) {
#pragma unroll
  for (int it = 0; it < 2; ++it) {
    int idx = it * 512 + tid;          // 16B-unit index, 0..1023
    int r = idx >> 3;                  // row 0..127
    int slot = idx & 7;
    int src = (slot ^ (r & 7)) << 3;   // short offset within the row
    gl16((char*)ldsb + idx * 16, gbase + (size_t)r * 1024 + src);
  }
}

__device__ __forceinline__ bf16x8 frag_ld(const short* hb, int row, int ks, int q4) {
  int slot = (ks * 4 + q4) ^ (row & 7);
  return *(const bf16x8*)((const char*)hb + row * 128 + slot * 16);
}

// ---------------------------------------------------------------------------
// Fused QKV GEMM: 256x256 tile, BK=64, 8-phase pipeline (unchanged).
__global__ __launch_bounds__(512, 2)
void qkv256_k(const short* __restrict__ A, const short* __restrict__ Bt3,
              short* __restrict__ q_bf, short* __restrict__ kpad,
              short* __restrict__ vpadT,
              const float* __restrict__ qsc, float kscale) {
  __shared__ __align__(16) short lds[65536];

  const int tid = threadIdx.x;
  const int lane = tid & 63, wid = tid >> 6;
  const int q4 = lane >> 4, l16 = lane & 15;
  const int wr = wid >> 2, wc = wid & 3;          // 2 M-waves x 4 N-waves

  const int id = blockIdx.x;
  const int xcd = id & 7, local = id >> 3;
  const int mm = xcd * 8 + local / 12, nn = local % 12;
  const int m0 = mm * 256, n0 = nn * 256;

  const short* Abase = A + (size_t)m0 * 1024;     // row-major [16384][1024]
  const short* Bbase = Bt3 + (size_t)n0 * 1024;   // 3 weights contiguous, [n][k]

  const f32x4 z4 = {0.f, 0.f, 0.f, 0.f};
  f32x4 acc[8][4];
#pragma unroll
  for (int i = 0; i < 8; ++i)
#pragma unroll
    for (int j = 0; j < 4; ++j) acc[i][j] = z4;

  stage_half(lds + 0 * 32768 + 0 * 8192, Abase, tid);
  stage_half(lds + 0 * 32768 + 1 * 8192, Abase + 128 * 1024, tid);
  stage_half(lds + 0 * 32768 + 2 * 8192, Bbase, tid);
  stage_half(lds + 0 * 32768 + 3 * 8192, Bbase + 128 * 1024, tid);
  stage_half(lds + 1 * 32768 + 2 * 8192, Bbase + 64, tid);
  stage_half(lds + 1 * 32768 + 3 * 8192, Bbase + 128 * 1024 + 64, tid);
  asm volatile("s_waitcnt vmcnt(4)" ::: "memory");
  __builtin_amdgcn_s_barrier();

  for (int kt = 0; kt < 16; ++kt) {
    const int buf = kt & 1;
    const short* Acur = lds + buf * 32768 + wr * 8192;
    const short* Bcur = lds + buf * 32768 + (2 + (wc >> 1)) * 8192;
    const int brow0 = (wc & 1) * 64;

    bf16x8 bfr[4][2];

    {
#pragma unroll
      for (int j = 0; j < 4; ++j)
#pragma unroll
        for (int ks = 0; ks < 2; ++ks)
          bfr[j][ks] = frag_ld(Bcur, brow0 + j * 16 + l16, ks, q4);
      bf16x8 afr[2][2];
#pragma unroll
      for (int m2 = 0; m2 < 2; ++m2)
#pragma unroll
        for (int ks = 0; ks < 2; ++ks)
          afr[m2][ks] = frag_ld(Acur, m2 * 16 + l16, ks, q4);
      if (kt < 15)
        stage_half(lds + (buf ^ 1) * 32768 + 0 * 8192, Abase + (size_t)(kt + 1) * 64, tid);
      asm volatile("s_waitcnt lgkmcnt(8)" ::: "memory");
      __builtin_amdgcn_s_barrier();
      asm volatile("s_waitcnt lgkmcnt(0)" ::: "memory");
      __builtin_amdgcn_s_setprio(1);
#pragma unroll
      for (int ks = 0; ks < 2; ++ks)
#pragma unroll
        for (int m2 = 0; m2 < 2; ++m2)
#pragma unroll
          for (int j = 0; j < 4; ++j)
            acc[m2][j] = __builtin_amdgcn_mfma_f32_16x16x32_bf16(
                afr[m2][ks], bfr[j][ks], acc[m2][j], 0, 0, 0);
      __builtin_amdgcn_s_setprio(0);
      __builtin_amdgcn_s_barrier();
    }

#pragma unroll
    for (int p = 1; p < 4; ++p) {
      bf16x8 afr[2][2];
#pragma unroll
      for (int m2 = 0; m2 < 2; ++m2)
#pragma unroll
        for (int ks = 0; ks < 2; ++ks)
          afr[m2][ks] = frag_ld(Acur, (p * 2 + m2) * 16 + l16, ks, q4);
      if (p == 1) {
        if (kt < 15)
          stage_half(lds + (buf ^ 1) * 32768 + 1 * 8192,
                     Abase + 128 * 1024 + (size_t)(kt + 1) * 64, tid);
      } else if (p == 2) {
        if (kt < 14)
          stage_half(lds + buf * 32768 + 2 * 8192, Bbase + (size_t)(kt + 2) * 64, tid);
      } else {
        if (kt < 14)
          stage_half(lds + buf * 32768 + 3 * 8192,
                     Bbase + 128 * 1024 + (size_t)(kt + 2) * 64, tid);
      }
      __builtin_amdgcn_s_barrier();
      asm volatile("s_waitcnt lgkmcnt(0)" ::: "memory");
      __builtin_amdgcn_s_setprio(1);
#pragma unroll
      for (int ks = 0; ks < 2; ++ks)
#pragma unroll
        for (int m2 = 0; m2 < 2; ++m2)
#pragma unroll
          for (int j = 0; j < 4; ++j)
            acc[p * 2 + m2][j] = __builtin_amdgcn_mfma_f32_16x16x32_bf16(
                afr[m2][ks], bfr[j][ks], acc[p * 2 + m2][j], 0, 0, 0);
      __builtin_amdgcn_s_setprio(0);
      if (p == 3) {
        if (kt < 14) asm volatile("s_waitcnt vmcnt(4)" ::: "memory");
        else         asm volatile("s_waitcnt vmcnt(0)" ::: "memory");
      }
      __builtin_amdgcn_s_barrier();
    }
  }

  const int w = n0 >> 10;          // 0=Q,1=K,2=V
  const int cw = n0 & 1023;
  const int b = m0 >> 13;
  const int s_base = (m0 & 8191) + wr * 128;

  if (w == 0) {
    float qsv[4];
#pragma unroll
    for (int j = 0; j < 4; ++j) qsv[j] = qsc[(cw + wc * 64 + j * 16 + l16) & 127];
#pragma unroll
    for (int m = 0; m < 8; ++m)
#pragma unroll
      for (int j = 0; j < 4; ++j)
#pragma unroll
        for (int rg = 0; rg < 4; ++rg) {
          int s = s_base + m * 16 + q4 * 4 + rg;
          int col = cw + wc * 64 + j * 16 + l16;
          int h = col >> 7, d = col & 127;
          int n = s >> 7, c = s & 127;
          q_bf[((size_t)(((b * 64 + n) * 8 + h) * 128 + c)) * 128 + d] =
              f2bf(acc[m][j][rg] * qsv[j]);
        }
  } else if (w == 1) {
#pragma unroll
    for (int m = 0; m < 8; ++m)
#pragma unroll
      for (int j = 0; j < 4; ++j)
#pragma unroll
        for (int rg = 0; rg < 4; ++rg) {
          int s = s_base + m * 16 + q4 * 4 + rg;
          int col = cw + wc * 64 + j * 16 + l16;
          int h = col >> 7, d = col & 127;
          kpad[((size_t)(b * 8 + h) * 8448 + 127 + s) * 128 + d] =
              f2bf(acc[m][j][rg] * kscale);
        }
  } else {
    short* T = lds;
#pragma unroll
    for (int hh = 0; hh < 2; ++hh) {
      __syncthreads();
      if ((wc >> 1) == hh) {
#pragma unroll
        for (int m = 0; m < 8; ++m)
#pragma unroll
          for (int j = 0; j < 4; ++j)
#pragma unroll
            for (int rg = 0; rg < 4; ++rg) {
              int sl = wr * 128 + m * 16 + q4 * 4 + rg;
              int dl = (wc & 1) * 64 + j * 16 + l16;
              T[dl * 264 + sl] = f2bf(acc[m][j][rg]);
            }
      }
      __syncthreads();
      const int h = (cw >> 7) + hh;
#pragma unroll
      for (int it = 0; it < 8; ++it) {
        int co = it * 512 + tid;
        int dd = co >> 5, s8 = (co & 31) * 8;
        *(bf16x8*)&vpadT[((size_t)(b * 8 + h) * 128 + dd) * 8448 + 127 + (m0 & 8191) + s8] =
            *(const bf16x8*)&T[dd * 264 + s8];
      }
    }
  }
}

// ---------------------------------------------------------------------------
// Post GEMM on the 256x256/8-phase template (unchanged).
__global__ __launch_bounds__(512, 2)
void post256_k(const short* __restrict__ A, const short* __restrict__ Bt,
               float* __restrict__ outf) {
  __shared__ __align__(16) short lds[65536];

  const int tid = threadIdx.x;
  const int lane = tid & 63, wid = tid >> 6;
  const int q4 = lane >> 4, l16 = lane & 15;
  const int wr = wid >> 2, wc = wid & 3;

  const int id = blockIdx.x;
  const int xcd = id & 7, local = id >> 3;      // local in [0,32)
  const int mm = xcd * 8 + (local >> 2), nn = local & 3;
  const int m0 = mm * 256, n0 = nn * 256;

  const short* Abase = A + (size_t)m0 * 1024;
  const short* Bbase = Bt + (size_t)n0 * 1024;

  const f32x4 z4 = {0.f, 0.f, 0.f, 0.f};
  f32x4 acc[8][4];
#pragma unroll
  for (int i = 0; i < 8; ++i)
#pragma unroll
    for (int j = 0; j < 4; ++j) acc[i][j] = z4;

  stage_half(lds + 0 * 32768 + 0 * 8192, Abase, tid);
  stage_half(lds + 0 * 32768 + 1 * 8192, Abase + 128 * 1024, tid);
  stage_half(lds + 0 * 32768 + 2 * 8192, Bbase, tid);
  stage_half(lds + 0 * 32768 + 3 * 8192, Bbase + 128 * 1024, tid);
  stage_half(lds + 1 * 32768 + 2 * 8192, Bbase + 64, tid);
  stage_half(lds + 1 * 32768 + 3 * 8192, Bbase + 128 * 1024 + 64, tid);
  asm volatile("s_waitcnt vmcnt(4)" ::: "memory");
  __builtin_amdgcn_s_barrier();

  for (int kt = 0; kt < 16; ++kt) {
    const int buf = kt & 1;
    const short* Acur = lds + buf * 32768 + wr * 8192;
    const short* Bcur = lds + buf * 32768 + (2 + (wc >> 1)) * 8192;
    const int brow0 = (wc & 1) * 64;

    bf16x8 bfr[4][2];

    {
#pragma unroll
      for (int j = 0; j < 4; ++j)
#pragma unroll
        for (int ks = 0; ks < 2; ++ks)
          bfr[j][ks] = frag_ld(Bcur, brow0 + j * 16 + l16, ks, q4);
      bf16x8 afr[2][2];
#pragma unroll
      for (int m2 = 0; m2 < 2; ++m2)
#pragma unroll
        for (int ks = 0; ks < 2; ++ks)
          afr[m2][ks] = frag_ld(Acur, m2 * 16 + l16, ks, q4);
      if (kt < 15)
        stage_half(lds + (buf ^ 1) * 32768 + 0 * 8192, Abase + (size_t)(kt + 1) * 64, tid);
      asm volatile("s_waitcnt lgkmcnt(8)" ::: "memory");
      __builtin_amdgcn_s_barrier();
      asm volatile("s_waitcnt lgkmcnt(0)" ::: "memory");
      __builtin_amdgcn_s_setprio(1);
#pragma unroll
      for (int ks = 0; ks < 2; ++ks)
#pragma unroll
        for (int m2 = 0; m2 < 2; ++m2)
#pragma unroll
          for (int j = 0; j < 4; ++j)
            acc[m2][j] = __builtin_amdgcn_mfma_f32_16x16x32_bf16(
                afr[m2][ks], bfr[j][ks], acc[m2][j], 0, 0, 0);
      __builtin_amdgcn_s_setprio(0);
      __builtin_amdgcn_s_barrier();
    }

#pragma unroll
    for (int p = 1; p < 4; ++p) {
      bf16x8 afr[2][2];
#pragma unroll
      for (int m2 = 0; m2 < 2; ++m2)
#pragma unroll
        for (int ks = 0; ks < 2; ++ks)
          afr[m2][ks] = frag_ld(Acur, (p * 2 + m2) * 16 + l16, ks, q4);
      if (p == 1) {
        if (kt < 15)
          stage_half(lds + (buf ^ 1) * 32768 + 1 * 8192,
                     Abase + 128 * 1024 + (size_t)(kt + 1) * 64, tid);
      } else if (p == 2) {
        if (kt < 14)
          stage_half(lds + buf * 32768 + 2 * 8192, Bbase + (size_t)(kt + 2) * 64, tid);
      } else {
        if (kt < 14)
          stage_half(lds + buf * 32768 + 3 * 8192,
                     Bbase + 128 * 1024 + (size_t)(kt + 2) * 64, tid);
      }
      __builtin_amdgcn_s_barrier();
      asm volatile("s_waitcnt lgkmcnt(0)" ::: "memory");
      __builtin_amdgcn_s_setprio(1);
#pragma unroll
      for (int ks = 0; ks < 2; ++ks)
#pragma unroll
        for (int m2 = 0; m2 < 2; ++m2)
#pragma unroll
          for (int j = 0; j < 4; ++j)
            acc[p * 2 + m2][j] = __builtin_amdgcn_mfma_f32_16x16x32_bf16(
                afr[m2][ks], bfr[j][ks], acc[p * 2 + m2][j], 0, 0, 0);
      __builtin_amdgcn_s_setprio(0);
      if (p == 3) {
        if (kt < 14) asm volatile("s_waitcnt vmcnt(4)" ::: "memory");
        else         asm volatile("s_waitcnt vmcnt(0)" ::: "memory");
      }
      __builtin_amdgcn_s_barrier();
    }
  }

#pragma unroll
  for (int m = 0; m < 8; ++m)
#pragma unroll
    for (int j = 0; j < 4; ++j)
#pragma unroll
      for (int rg = 0; rg < 4; ++rg) {
        const int row = m0 + wr * 128 + m * 16 + q4 * 4 + rg;
        const int col = n0 + wc * 64 + j * 16 + l16;
        outf[(size_t)row * 1024 + col] = acc[m][j][rg];
      }
}

// ---------------------------------------------------------------------------
// REL GEMM (counted-vmcnt double-buffer, unchanged from R10).
__global__ __launch_bounds__(256, 2)
void rel_gemm_k(const short* __restrict__ A, const short* __restrict__ Bt,
                short* __restrict__ relk) {
  __shared__ __align__(16) short As[2][128 * 32];
  __shared__ __align__(16) short Bs[2][128 * 32];

  const int tid = threadIdx.x;
  const int lane = tid & 63, wid = tid >> 6;
  const int q4 = lane >> 4, l16 = lane & 15;
  const int wr = wid >> 1, wc = wid & 1;
  const int m0 = blockIdx.x * 128, n0 = blockIdx.y * 128;

  const f32x4 z4 = {0.f, 0.f, 0.f, 0.f};
  f32x4 acc[4][4];
#pragma unroll
  for (int i = 0; i < 4; ++i)
#pragma unroll
    for (int j = 0; j < 4; ++j) acc[i][j] = z4;

  const int r0 = tid >> 2, s0_ = (tid & 3) * 8;

  {
    gl16(&As[0][tid * 8],         A  + (size_t)(m0 + r0) * 1024 + s0_);
    gl16(&Bs[0][tid * 8],         Bt + (size_t)(n0 + r0) * 1024 + s0_);
    gl16(&As[0][(256 + tid) * 8], A  + (size_t)(m0 + 64 + r0) * 1024 + s0_);
    gl16(&Bs[0][(256 + tid) * 8], Bt + (size_t)(n0 + 64 + r0) * 1024 + s0_);
  }

  for (int kt = 0; kt < 32; ++kt) {
    const int buf = kt & 1;
    if (kt < 31) {
      const int kk = (kt + 1) * 32;
      gl16(&As[buf ^ 1][tid * 8],         A  + (size_t)(m0 + r0) * 1024 + kk + s0_);
      gl16(&Bs[buf ^ 1][tid * 8],         Bt + (size_t)(n0 + r0) * 1024 + kk + s0_);
      gl16(&As[buf ^ 1][(256 + tid) * 8], A  + (size_t)(m0 + 64 + r0) * 1024 + kk + s0_);
      gl16(&Bs[buf ^ 1][(256 + tid) * 8], Bt + (size_t)(n0 + 64 + r0) * 1024 + kk + s0_);
      asm volatile("s_waitcnt vmcnt(4)" ::: "memory");
    } else {
      asm volatile("s_waitcnt vmcnt(0)" ::: "memory");
    }
    __builtin_amdgcn_s_barrier();

    bf16x8 af[4], bfv[4];
#pragma unroll
    for (int i = 0; i < 4; ++i)
      af[i] = *(const bf16x8*)&As[buf][(wr * 64 + i * 16 + l16) * 32 + q4 * 8];
#pragma unroll
    for (int j = 0; j < 4; ++j)
      bfv[j] = *(const bf16x8*)&Bs[buf][(wc * 64 + j * 16 + l16) * 32 + q4 * 8];
#pragma unroll
    for (int i = 0; i < 4; ++i)
#pragma unroll
      for (int j = 0; j < 4; ++j)
        acc[i][j] = __builtin_amdgcn_mfma_f32_16x16x32_bf16(af[i], bfv[j], acc[i][j], 0, 0, 0);
    __builtin_amdgcn_s_barrier();
  }

#pragma unroll
  for (int i = 0; i < 4; ++i)
#pragma unroll
    for (int j = 0; j < 4; ++j)
#pragma unroll
      for (int rg = 0; rg < 4; ++rg) {
        const int row = m0 + wr * 64 + i * 16 + q4 * 4 + rg;
        const int col = n0 + wc * 64 + j * 16 + l16;
        int h = col >> 7, d = col & 127;
        relk[(size_t)(h * 384 + row) * 128 + d] = f2bf(acc[i][j][rg]);
      }
}

// ---------------------------------------------------------------------------
// R12 bd GEMM, single-stage: K=128 staged entirely (A 32KB + B 32KB slabs),
// one drain + one barrier, then 4x16 MFMA with no intervening syncs.
// LDS slabs [kc][row][32] (attn-style). Epilogue rel-shift unchanged.
__global__ __launch_bounds__(256, 2)
void bd_gemm_k(const short* __restrict__ qb_b, const short* __restrict__ relk,
               short* __restrict__ bds) {
  __shared__ __align__(16) short As[4 * 128 * 32];  // 32 KB
  __shared__ __align__(16) short Bs[4 * 128 * 32];  // 32 KB
  const int tid = threadIdx.x;
  const int lane = tid & 63, wid = tid >> 6;
  const int q4 = lane >> 4, l16 = lane & 15;
  const int wr = wid >> 1, wc = wid & 1;
  const int p0 = blockIdx.x * 128;
  const int nh = blockIdx.y;          // n*8 + h  (within b)
  const int h = nh & 7;
  const short* A = qb_b + (size_t)nh * 16384;
  const short* Bt = relk + (size_t)h * (384 * 128);
  short* bdo = bds + (size_t)nh * 49152;

  // stage the full 128x128 A and B tiles (8 gl16 each per thread)
#pragma unroll
  for (int it = 0; it < 8; ++it) {
    int ci = it * 256 + tid;                       // [0,2048)
    int dc = ci >> 9, rr = (ci >> 2) & 127, sub = (ci & 3) * 8;
    gl16(&As[ci * 8], A + (size_t)rr * 128 + dc * 32 + sub);
  }
#pragma unroll
  for (int it = 0; it < 8; ++it) {
    int ci = it * 256 + tid;
    int dc = ci >> 9, rr = (ci >> 2) & 127, sub = (ci & 3) * 8;
    gl16(&Bs[ci * 8], Bt + (size_t)(p0 + rr) * 128 + dc * 32 + sub);
  }
  asm volatile("s_waitcnt vmcnt(0)" ::: "memory");
  __builtin_amdgcn_s_barrier();

  const f32x4 z4 = {0.f, 0.f, 0.f, 0.f};
  f32x4 acc[4][4];
#pragma unroll
  for (int i = 0; i < 4; ++i)
#pragma unroll
    for (int j = 0; j < 4; ++j) acc[i][j] = z4;

#pragma unroll
  for (int dc = 0; dc < 4; ++dc) {
    bf16x8 af[4], bfv[4];
#pragma unroll
    for (int i = 0; i < 4; ++i)
      af[i] = *(const bf16x8*)&As[dc * 4096 + (wr * 64 + i * 16 + l16) * 32 + q4 * 8];
#pragma unroll
    for (int j = 0; j < 4; ++j)
      bfv[j] = *(const bf16x8*)&Bs[dc * 4096 + (wc * 64 + j * 16 + l16) * 32 + q4 * 8];
#pragma unroll
    for (int i = 0; i < 4; ++i)
#pragma unroll
      for (int j = 0; j < 4; ++j)
        acc[i][j] = __builtin_amdgcn_mfma_f32_16x16x32_bf16(af[i], bfv[j], acc[i][j], 0, 0, 0);
  }

  // rel-shift: (r,p) -> (c,k): flat r*384+p == c*383+k, drop c >= 128
#pragma unroll
  for (int i = 0; i < 4; ++i)
#pragma unroll
    for (int j = 0; j < 4; ++j)
#pragma unroll
      for (int rg = 0; rg < 4; ++rg) {
        int r = wr * 64 + i * 16 + q4 * 4 + rg;
        int p = p0 + wc * 64 + j * 16 + l16;
        int t = r + p;
        int c = (t < 383) ? r : (r + 1);
        int k = (t < 383) ? t : (t - 383);
        if (c < 128) {
          int tt = k >> 7, jj = (k >> 4) & 7, ll = k & 15;
          int wa = c >> 5, ia = (c >> 4) & 1, qa = (c >> 2) & 3, ra = c & 3;
          bdo[((((size_t)tt * 8 + jj) * 256) + wa * 64 + qa * 16 + ll) * 8 + ia * 4 + ra] =
              f2bf(acc[i][j][rg]);
        }
      }
}

// ---------------------------------------------------------------------------
// R10 fused local attention (reverted verbatim): counted-vmcnt pipeline +
// XCD head pinning + bd register preload.
__global__ __launch_bounds__(256, 2)
void attn_k(const short* __restrict__ qb_b, const short* __restrict__ kpad,
            const short* __restrict__ vpadT, const short* __restrict__ bds,
            short* __restrict__ attnout, int b) {
  __shared__ __align__(16) short Ks[4 * 128 * 32]; // K slabs [dc][key][32]
  __shared__ __align__(16) short Vs[4 * 128 * 32]; // V slabs [kc][d][32keys]
  __shared__ __align__(16) short Ps[64 * 128];     // Q stage -> P tile (XOR)

  const int tid = threadIdx.x;
  const int lane = tid & 63, wid = tid >> 6;
  const int q4 = lane >> 4, l16 = lane & 15;
  const int bx = blockIdx.x;
  const int h = bx & 7;               // XCD-pinned head
  const int local = bx >> 3;          // [0,128)
  const int n = local >> 1, qh = local & 1;
  const int nh = n * 8 + h;

  const short* qtile = qb_b + (size_t)nh * 16384 + qh * 64 * 128;
  const short* kbase = kpad + ((size_t)(b * 8 + h) * 8448 + n * 128) * 128;
  const short* vtb = vpadT + (size_t)(b * 8 + h) * 128 * 8448 + n * 128;
  const short* bdb = bds + (size_t)nh * 49152;

  // ---- prologue: Q -> Ps, bd fragments -> regs, K(0) -> Ks
#pragma unroll
  for (int it = 0; it < 4; ++it) {
    int ci = it * 256 + tid;                     // [0,1024)
    int dc = ci >> 8, rr = (ci >> 2) & 63, sub = (ci & 3) * 8;
    gl16(&Ps[ci * 8], qtile + rr * 128 + dc * 32 + sub);
  }
  asm volatile("" ::: "memory");       // keep Q gl16 oldest

  // preload ALL bd fragments (3 tiles x 8 j x 8B = 48 VGPRs)
  const int bdoff = ((qh * 2 + (wid >> 1)) * 64 + q4 * 16 + l16) * 8 + (wid & 1) * 4;
  s16x4 bdva[3][8];
#pragma unroll
  for (int t = 0; t < 3; ++t)
#pragma unroll
    for (int j = 0; j < 8; ++j)
      bdva[t][j] = *(const s16x4*)&bdb[(size_t)(t * 8 + j) * 2048 + bdoff];
  asm volatile("" ::: "memory");       // bd loads older than K(0)

#pragma unroll
  for (int it = 0; it < 8; ++it) {
    int ci = it * 256 + tid;
    int dc = ci >> 9, rr = (ci >> 2) & 127, sub = (ci & 3) * 8;
    gl16(&Ks[ci * 8], kbase + (size_t)rr * 128 + dc * 32 + sub);
  }
  asm volatile("s_waitcnt vmcnt(8)" ::: "memory");  // Q + bd done; K(0) in flight
  asm volatile("s_barrier" ::: "memory");
  bf16x8 qf[4];
#pragma unroll
  for (int dc = 0; dc < 4; ++dc)
    qf[dc] = *(const bf16x8*)&Ps[dc * 2048 + (wid * 16 + l16) * 32 + q4 * 8];
  asm volatile("s_waitcnt lgkmcnt(0)" ::: "memory"); // Q reads retired

  const f32x4 z4 = {0.f, 0.f, 0.f, 0.f};
  f32x4 acco[8];
#pragma unroll
  for (int j = 0; j < 8; ++j) acco[j] = z4;
  float rsum[4] = {};

#pragma unroll
  for (int t = 0; t < 3; ++t) {
    asm volatile("s_barrier" ::: "memory");  // (A) Vs/Ps free

    // stage V(t) -> Vs (waited only before PV)
#pragma unroll
    for (int it = 0; it < 8; ++it) {
      int ci = it * 256 + tid;
      int kc = ci >> 9, dd = (ci >> 2) & 127, sub = (ci & 3) * 8;
      gl16(&Vs[ci * 8], vtb + (size_t)dd * 8448 + t * 128 + kc * 32 + sub);
    }

    asm volatile("s_waitcnt vmcnt(8)" ::: "memory"); // K(t) done, V in flight
    asm volatile("s_barrier" ::: "memory");  // (B) K visible to all waves

    // S = Q @ K^T  (16 rows per wave)
    f32x4 accs[8];
#pragma unroll
    for (int j = 0; j < 8; ++j) accs[j] = z4;
    __builtin_amdgcn_s_setprio(1);
#pragma unroll
    for (int dc = 0; dc < 4; ++dc) {
      bf16x8 kf[8];
#pragma unroll
      for (int j = 0; j < 8; ++j)
        kf[j] = *(const bf16x8*)&Ks[dc * 4096 + (j * 16 + l16) * 32 + q4 * 8];
#pragma unroll
      for (int j = 0; j < 8; ++j)
        accs[j] = __builtin_amdgcn_mfma_f32_16x16x32_bf16(qf[dc], kf[j], accs[j], 0, 0, 0);
    }
    __builtin_amdgcn_s_setprio(0);

    // logits: s = ac + bd;  w = exp2(-100*log2e / (exp2(s*2*log2e/50) + 1))
#pragma unroll
    for (int j = 0; j < 8; ++j) {
      const int kg = t * 128 + j * 16 + l16;
#pragma unroll
      for (int rg = 0; rg < 4; ++rg) {
        float sv = accs[j][rg] + bf2f((unsigned short)bdva[t][j][rg]);
        float tt = exp2f(sv * 0.057707801635558534f);
        float wgt = exp2f(-144.26950408889634f * __fdividef(1.0f, tt + 1.0f));
        wgt = (kg < 383) ? wgt : 0.0f;
        accs[j][rg] = wgt;
        rsum[rg] += wgt;
      }
    }

    asm volatile("s_barrier" ::: "memory");  // (C) all waves done reading Ks

    // stage K(t+1) -> Ks (overlaps P-write + PV; waited at top of t+1)
    if (t < 2) {
#pragma unroll
      for (int it = 0; it < 8; ++it) {
        int ci = it * 256 + tid;
        int dc = ci >> 9, rr = (ci >> 2) & 127, sub = (ci & 3) * 8;
        gl16(&Ks[ci * 8], kbase + (size_t)((t + 1) * 128 + rr) * 128 + dc * 32 + sub);
      }
    }

    // write P tile (granule-XOR layout: granule g ^= c&7)
#pragma unroll
    for (int j = 0; j < 8; ++j)
#pragma unroll
      for (int rg = 0; rg < 4; ++rg) {
        int c = wid * 16 + q4 * 4 + rg;
        int kl = j * 16 + l16;
        int g = (kl >> 3) ^ (c & 7);
        Ps[c * 128 + g * 8 + (kl & 7)] = f2bf(accs[j][rg]);
      }

    if (t < 2) asm volatile("s_waitcnt vmcnt(8)" ::: "memory"); // V(t) done, K(t+1) in flight
    else       asm volatile("s_waitcnt vmcnt(0)" ::: "memory"); // final tile: drain
    asm volatile("s_waitcnt lgkmcnt(0)" ::: "memory");          // P writes committed
    asm volatile("s_barrier" ::: "memory");  // (D) V + P ready

    // PV over kc = 0..3
    __builtin_amdgcn_s_setprio(1);
#pragma unroll
    for (int kc = 0; kc < 4; ++kc) {
      int c = wid * 16 + l16;
      int g = (kc * 4 + q4) ^ (c & 7);
      bf16x8 pf = *(const bf16x8*)&Ps[c * 128 + g * 8];
      bf16x8 vf[8];
#pragma unroll
      for (int j = 0; j < 8; ++j)
        vf[j] = *(const bf16x8*)&Vs[kc * 4096 + (j * 16 + l16) * 32 + q4 * 8];
#pragma unroll
      for (int j = 0; j < 8; ++j)
        acco[j] = __builtin_amdgcn_mfma_f32_16x16x32_bf16(pf, vf[j], acco[j], 0, 0, 0);
    }
    __builtin_amdgcn_s_setprio(0);
  }

  // row-sum butterfly over the 16-lane group (cols), normalize, write bf16
  float rinv[4];
#pragma unroll
  for (int rg = 0; rg < 4; ++rg) {
    float rs = rsum[rg];
    rs += __shfl_xor(rs, 1);
    rs += __shfl_xor(rs, 2);
    rs += __shfl_xor(rs, 4);
    rs += __shfl_xor(rs, 8);
    rinv[rg] = __fdividef(1.0f, rs);
  }
#pragma unroll
  for (int j = 0; j < 8; ++j)
#pragma unroll
    for (int rg = 0; rg < 4; ++rg) {
      int srow = n * 128 + qh * 64 + wid * 16 + q4 * 4 + rg;
      int col = h * 128 + j * 16 + l16;
      attnout[((size_t)b * 8192 + srow) * 1024 + col] = f2bf(acco[j][rg] * rinv[rg]);
    }
}

// ---------------------------------------------------------------------------
extern "C" void kernel_launch(void* const* d_in, const int* in_sizes, int n_in,
                              void* d_out, int out_size, void* d_ws, size_t ws_size,
                              hipStream_t stream) {
  (void)in_sizes; (void)n_in; (void)out_size; (void)ws_size;
  const float* hs    = (const float*)d_in[0];
  const float* pemb  = (const float*)d_in[1];
  const float* Wq    = (const float*)d_in[2];
  const float* Wk    = (const float*)d_in[3];
  const float* Wv    = (const float*)d_in[4];
  const float* Wrel  = (const float*)d_in[5];
  const float* Wpost = (const float*)d_in[6];
  const float* pds   = (const float*)d_in[7];
  float* out = (float*)d_out;

  char* w = (char*)d_ws;
  auto alloc = [&](size_t bytes) -> char* {
    char* p = w; w += (bytes + 255) & ~(size_t)255; return p;
  };
  short* hs_bf   = (short*)alloc((size_t)16384 * 1024 * 2); // 33.5 MB (attnout aliases later)
  short* pos_bf  = (short*)alloc((size_t)384 * 1024 * 2);
  short* Wq_t    = (short*)alloc((size_t)1024 * 1024 * 2);  // Wq_t..Wpost_t contiguous
  short* Wk_t    = (short*)alloc((size_t)1024 * 1024 * 2);
  short* Wv_t    = (short*)alloc((size_t)1024 * 1024 * 2);
  short* Wrel_t  = (short*)alloc((size_t)1024 * 1024 * 2);
  short* Wpost_t = (short*)alloc((size_t)1024 * 1024 * 2);
  float* qsc     = (float*)alloc(512);
  short* q_bf    = (short*)alloc((size_t)2 * 64 * 8 * 128 * 128 * 2); // 33.5 MB
  short* kpad    = (short*)alloc((size_t)2 * 8 * 8448 * 128 * 2);     // 34.6 MB
  short* vpadT   = (short*)alloc((size_t)2 * 8 * 128 * 8448 * 2);     // 34.6 MB
  short* relk    = (short*)alloc((size_t)8 * 384 * 128 * 2);
  short* bds     = (short*)alloc((size_t)64 * 8 * 128 * 384 * 2);     // 50.3 MB, per-b (reused)
  short* attnout = hs_bf;  // hs_bf dead after QKV projection; attn starts after
  // total ~199 MB (< 232 MB known-good)

  const float kscale = (float)(log1p(exp(1.0)) / log(2.0));
  const double qsb = (1.0 / sqrt(128.0)) / log(2.0);

  cvt_bf16_k<<<16384, 256, 0, stream>>>(hs, hs_bf, 16384 * 1024);
  cvt_bf16_k<<<384, 256, 0, stream>>>(pemb, pos_bf, 384 * 1024);
  wtrans5_k<<<dim3(16, 16, 5), 256, 0, stream>>>(Wq, Wk, Wv, Wrel, Wpost, Wq_t);
  qscale_k<<<1, 128, 0, stream>>>(pds, qsc, qsb);
  kpadzero_k<<<dim3(256, 16), 128, 0, stream>>>(kpad);
  vpadzero_k<<<2048, 256, 0, stream>>>(vpadT);

  qkv256_k<<<768, 512, 0, stream>>>(hs_bf, Wq_t, q_bf, kpad, vpadT, qsc, kscale);
  rel_gemm_k<<<dim3(3, 8), 256, 0, stream>>>(pos_bf, Wrel_t, relk);

  for (int b = 0; b < 2; ++b) {
    const short* qb_b = q_bf + (size_t)b * 64 * 8 * 128 * 128;
    bd_gemm_k<<<dim3(3, 512), 256, 0, stream>>>(qb_b, relk, bds);
    attn_k<<<1024, 256, 0, stream>>>(qb_b, kpad, vpadT, bds, attnout, b);
  }

  post256_k<<<256, 512, 0, stream>>>(attnout, Wpost_t, out);
}

// Round 8
// 483.277 us; speedup vs baseline: 1.1409x; 1.0036x over previous
//
#include <hip/hip_runtime.h>
#include <cmath>

// ---------------------------------------------------------------------------
// Gemma4 audio attention, MI355X bf16-MFMA pipeline.
// B=2 S=8192 HID=1024 H=8 D=128 CHUNK=128 PAST=127 FUT=128 CTX=383 POS=384
// R13: (1) attn_k + bd_gemm slab LDS XOR-swizzle (slot ^= (row>>1)&3):
//      the [row][32] slabs were an 8-way bank conflict on every K/V/Q/A/B
//      fragment read (same defect class fixed in qkv at R7). Linear gl16
//      dest + inverse-permuted global source + same XOR on reads.
//      (2) attn merged into ONE 2048-block launch (counter visibility),
//      guarded by ws_size (needs +50.3MB second bds); falls back to the
//      per-b path if the workspace is too small. Everything else R12.
// ---------------------------------------------------------------------------

using bf16x8 = __attribute__((ext_vector_type(8))) short;
using f32x4  = __attribute__((ext_vector_type(4))) float;
using s16x4  = __attribute__((ext_vector_type(4))) short;

__device__ __forceinline__ short f2bf(float f) {
  unsigned u = __float_as_uint(f);
  u = (u + 0x7FFF + ((u >> 16) & 1)) >> 16;   // RNE
  return (short)u;
}
__device__ __forceinline__ float bf2f(unsigned short s) {
  return __uint_as_float(((unsigned)s) << 16);
}

// async global->LDS, 16B per lane. LDS dest must be wave-uniform base + lane*16.
__device__ __forceinline__ void gl16(void* lds, const void* gptr) {
  __builtin_amdgcn_global_load_lds(
      (const __attribute__((address_space(1))) unsigned int*)gptr,
      (__attribute__((address_space(3))) unsigned int*)lds, 16, 0, 0);
}

// ---------------------------------------------------------------------------
// elementwise fp32 -> bf16
__global__ void cvt_bf16_k(const float* __restrict__ in, short* __restrict__ out, int n) {
  int i = (blockIdx.x * 256 + threadIdx.x) * 4;
  if (i + 3 < n) {
    float4 v = *(const float4*)&in[i];
    s16x4 o;
    o[0] = f2bf(v.x); o[1] = f2bf(v.y); o[2] = f2bf(v.z); o[3] = f2bf(v.w);
    *(s16x4*)&out[i] = o;
  }
}

// All 5 weights (1024x1024 f32, [k][n]) -> Wt (bf16, [n][k]), one launch.
__global__ void wtrans5_k(const float* __restrict__ W0, const float* __restrict__ W1,
                          const float* __restrict__ W2, const float* __restrict__ W3,
                          const float* __restrict__ W4, short* __restrict__ Wt_all) {
  __shared__ float T[64 * 65];
  const int tid = threadIdx.x;
  const int bx = blockIdx.x, by = blockIdx.y; // bx: n-tile, by: k-tile
  const int z = blockIdx.z;
  const float* W = W0;
  if (z == 1) W = W1;
  else if (z == 2) W = W2;
  else if (z == 3) W = W3;
  else if (z == 4) W = W4;
  short* Wt = Wt_all + (size_t)z * 1024 * 1024;
#pragma unroll
  for (int it = 0; it < 4; ++it) {
    int ci = it * 256 + tid;
    int k = ci >> 4, n4 = (ci & 15) * 4;
    float4 v = *(const float4*)&W[(size_t)(by * 64 + k) * 1024 + bx * 64 + n4];
    T[k * 65 + n4 + 0] = v.x;
    T[k * 65 + n4 + 1] = v.y;
    T[k * 65 + n4 + 2] = v.z;
    T[k * 65 + n4 + 3] = v.w;
  }
  __syncthreads();
#pragma unroll
  for (int it = 0; it < 2; ++it) {
    int co = it * 256 + tid;
    int nn = co >> 3, k8 = (co & 7) * 8;
    bf16x8 o;
#pragma unroll
    for (int jj = 0; jj < 8; ++jj) o[jj] = f2bf(T[(k8 + jj) * 65 + nn]);
    *(bf16x8*)&Wt[(size_t)(bx * 64 + nn) * 1024 + by * 64 + k8] = o;
  }
}

// qscale[d] = (1/sqrt(128))/ln2 * softplus(pds[d])
__global__ void qscale_k(const float* __restrict__ pds, float* __restrict__ qs, double qsb) {
  int d = threadIdx.x;
  double x = (double)pds[d];
  qs[d] = (float)(qsb * log1p(exp(x)));
}

// zero vpadT pad columns: keys [0,127) and [8319,8448)
__global__ void vpadzero_k(short* __restrict__ vpadT) {
  int row = blockIdx.x;                 // (b*8+h)*128 + d   (2048 rows)
  int t = threadIdx.x;                  // 256
  int key = (t < 127) ? t : (8192 + t); // 0..126 and 8319..8447
  vpadT[(size_t)row * 8448 + key] = 0;
}

// zero kpad pad rows only: keys [0,127) and [8319,8448).
__global__ void kpadzero_k(short* __restrict__ kpad) {
  int bx = blockIdx.x;                  // 0..255 pad-row index
  int bh = blockIdx.y;                  // b*8+h, 0..15
  int key = (bx < 127) ? bx : (8192 + bx);
  kpad[((size_t)bh * 8448 + key) * 128 + threadIdx.x] = 0;
}

// ---------------------------------------------------------------------------
// 256x256/8-phase GEMM building blocks.
__device__ __forceinline__ void stage_half(short* ldsb, const short* gbase, int tid) {
#pragma unroll
  for (int it = 0; it < 2; ++it) {
    int idx = it * 512 + tid;          // 16B-unit index, 0..1023
    int r = idx >> 3;                  // row 0..127
    int slot = idx & 7;
    int src = (slot ^ (r & 7)) << 3;   // short offset within the row
    gl16((char*)ldsb + idx * 16, gbase + (size_t)r * 1024 + src);
  }
}

__device__ __forceinline__ bf16x8 frag_ld(const short* hb, int row, int ks, int q4) {
  int slot = (ks * 4 + q4) ^ (row & 7);
  return *(const bf16x8*)((const char*)hb + row * 128 + slot * 16);
}

// ---------------------------------------------------------------------------
// Fused QKV GEMM: 256x256 tile, BK=64, 8-phase pipeline (unchanged).
__global__ __launch_bounds__(512, 2)
void qkv256_k(const short* __restrict__ A, const short* __restrict__ Bt3,
              short* __restrict__ q_bf, short* __restrict__ kpad,
              short* __restrict__ vpadT,
              const float* __restrict__ qsc, float kscale) {
  __shared__ __align__(16) short lds[65536];

  const int tid = threadIdx.x;
  const int lane = tid & 63, wid = tid >> 6;
  const int q4 = lane >> 4, l16 = lane & 15;
  const int wr = wid >> 2, wc = wid & 3;          // 2 M-waves x 4 N-waves

  const int id = blockIdx.x;
  const int xcd = id & 7, local = id >> 3;
  const int mm = xcd * 8 + local / 12, nn = local % 12;
  const int m0 = mm * 256, n0 = nn * 256;

  const short* Abase = A + (size_t)m0 * 1024;     // row-major [16384][1024]
  const short* Bbase = Bt3 + (size_t)n0 * 1024;   // 3 weights contiguous, [n][k]

  const f32x4 z4 = {0.f, 0.f, 0.f, 0.f};
  f32x4 acc[8][4];
#pragma unroll
  for (int i = 0; i < 8; ++i)
#pragma unroll
    for (int j = 0; j < 4; ++j) acc[i][j] = z4;

  stage_half(lds + 0 * 32768 + 0 * 8192, Abase, tid);
  stage_half(lds + 0 * 32768 + 1 * 8192, Abase + 128 * 1024, tid);
  stage_half(lds + 0 * 32768 + 2 * 8192, Bbase, tid);
  stage_half(lds + 0 * 32768 + 3 * 8192, Bbase + 128 * 1024, tid);
  stage_half(lds + 1 * 32768 + 2 * 8192, Bbase + 64, tid);
  stage_half(lds + 1 * 32768 + 3 * 8192, Bbase + 128 * 1024 + 64, tid);
  asm volatile("s_waitcnt vmcnt(4)" ::: "memory");
  __builtin_amdgcn_s_barrier();

  for (int kt = 0; kt < 16; ++kt) {
    const int buf = kt & 1;
    const short* Acur = lds + buf * 32768 + wr * 8192;
    const short* Bcur = lds + buf * 32768 + (2 + (wc >> 1)) * 8192;
    const int brow0 = (wc & 1) * 64;

    bf16x8 bfr[4][2];

    {
#pragma unroll
      for (int j = 0; j < 4; ++j)
#pragma unroll
        for (int ks = 0; ks < 2; ++ks)
          bfr[j][ks] = frag_ld(Bcur, brow0 + j * 16 + l16, ks, q4);
      bf16x8 afr[2][2];
#pragma unroll
      for (int m2 = 0; m2 < 2; ++m2)
#pragma unroll
        for (int ks = 0; ks < 2; ++ks)
          afr[m2][ks] = frag_ld(Acur, m2 * 16 + l16, ks, q4);
      if (kt < 15)
        stage_half(lds + (buf ^ 1) * 32768 + 0 * 8192, Abase + (size_t)(kt + 1) * 64, tid);
      asm volatile("s_waitcnt lgkmcnt(8)" ::: "memory");
      __builtin_amdgcn_s_barrier();
      asm volatile("s_waitcnt lgkmcnt(0)" ::: "memory");
      __builtin_amdgcn_s_setprio(1);
#pragma unroll
      for (int ks = 0; ks < 2; ++ks)
#pragma unroll
        for (int m2 = 0; m2 < 2; ++m2)
#pragma unroll
          for (int j = 0; j < 4; ++j)
            acc[m2][j] = __builtin_amdgcn_mfma_f32_16x16x32_bf16(
                afr[m2][ks], bfr[j][ks], acc[m2][j], 0, 0, 0);
      __builtin_amdgcn_s_setprio(0);
      __builtin_amdgcn_s_barrier();
    }

#pragma unroll
    for (int p = 1; p < 4; ++p) {
      bf16x8 afr[2][2];
#pragma unroll
      for (int m2 = 0; m2 < 2; ++m2)
#pragma unroll
        for (int ks = 0; ks < 2; ++ks)
          afr[m2][ks] = frag_ld(Acur, (p * 2 + m2) * 16 + l16, ks, q4);
      if (p == 1) {
        if (kt < 15)
          stage_half(lds + (buf ^ 1) * 32768 + 1 * 8192,
                     Abase + 128 * 1024 + (size_t)(kt + 1) * 64, tid);
      } else if (p == 2) {
        if (kt < 14)
          stage_half(lds + buf * 32768 + 2 * 8192, Bbase + (size_t)(kt + 2) * 64, tid);
      } else {
        if (kt < 14)
          stage_half(lds + buf * 32768 + 3 * 8192,
                     Bbase + 128 * 1024 + (size_t)(kt + 2) * 64, tid);
      }
      __builtin_amdgcn_s_barrier();
      asm volatile("s_waitcnt lgkmcnt(0)" ::: "memory");
      __builtin_amdgcn_s_setprio(1);
#pragma unroll
      for (int ks = 0; ks < 2; ++ks)
#pragma unroll
        for (int m2 = 0; m2 < 2; ++m2)
#pragma unroll
          for (int j = 0; j < 4; ++j)
            acc[p * 2 + m2][j] = __builtin_amdgcn_mfma_f32_16x16x32_bf16(
                afr[m2][ks], bfr[j][ks], acc[p * 2 + m2][j], 0, 0, 0);
      __builtin_amdgcn_s_setprio(0);
      if (p == 3) {
        if (kt < 14) asm volatile("s_waitcnt vmcnt(4)" ::: "memory");
        else         asm volatile("s_waitcnt vmcnt(0)" ::: "memory");
      }
      __builtin_amdgcn_s_barrier();
    }
  }

  const int w = n0 >> 10;          // 0=Q,1=K,2=V
  const int cw = n0 & 1023;
  const int b = m0 >> 13;
  const int s_base = (m0 & 8191) + wr * 128;

  if (w == 0) {
    float qsv[4];
#pragma unroll
    for (int j = 0; j < 4; ++j) qsv[j] = qsc[(cw + wc * 64 + j * 16 + l16) & 127];
#pragma unroll
    for (int m = 0; m < 8; ++m)
#pragma unroll
      for (int j = 0; j < 4; ++j)
#pragma unroll
        for (int rg = 0; rg < 4; ++rg) {
          int s = s_base + m * 16 + q4 * 4 + rg;
          int col = cw + wc * 64 + j * 16 + l16;
          int h = col >> 7, d = col & 127;
          int n = s >> 7, c = s & 127;
          q_bf[((size_t)(((b * 64 + n) * 8 + h) * 128 + c)) * 128 + d] =
              f2bf(acc[m][j][rg] * qsv[j]);
        }
  } else if (w == 1) {
#pragma unroll
    for (int m = 0; m < 8; ++m)
#pragma unroll
      for (int j = 0; j < 4; ++j)
#pragma unroll
        for (int rg = 0; rg < 4; ++rg) {
          int s = s_base + m * 16 + q4 * 4 + rg;
          int col = cw + wc * 64 + j * 16 + l16;
          int h = col >> 7, d = col & 127;
          kpad[((size_t)(b * 8 + h) * 8448 + 127 + s) * 128 + d] =
              f2bf(acc[m][j][rg] * kscale);
        }
  } else {
    short* T = lds;
#pragma unroll
    for (int hh = 0; hh < 2; ++hh) {
      __syncthreads();
      if ((wc >> 1) == hh) {
#pragma unroll
        for (int m = 0; m < 8; ++m)
#pragma unroll
          for (int j = 0; j < 4; ++j)
#pragma unroll
            for (int rg = 0; rg < 4; ++rg) {
              int sl = wr * 128 + m * 16 + q4 * 4 + rg;
              int dl = (wc & 1) * 64 + j * 16 + l16;
              T[dl * 264 + sl] = f2bf(acc[m][j][rg]);
            }
      }
      __syncthreads();
      const int h = (cw >> 7) + hh;
#pragma unroll
      for (int it = 0; it < 8; ++it) {
        int co = it * 512 + tid;
        int dd = co >> 5, s8 = (co & 31) * 8;
        *(bf16x8*)&vpadT[((size_t)(b * 8 + h) * 128 + dd) * 8448 + 127 + (m0 & 8191) + s8] =
            *(const bf16x8*)&T[dd * 264 + s8];
      }
    }
  }
}

// ---------------------------------------------------------------------------
// Post GEMM on the 256x256/8-phase template (unchanged).
__global__ __launch_bounds__(512, 2)
void post256_k(const short* __restrict__ A, const short* __restrict__ Bt,
               float* __restrict__ outf) {
  __shared__ __align__(16) short lds[65536];

  const int tid = threadIdx.x;
  const int lane = tid & 63, wid = tid >> 6;
  const int q4 = lane >> 4, l16 = lane & 15;
  const int wr = wid >> 2, wc = wid & 3;

  const int id = blockIdx.x;
  const int xcd = id & 7, local = id >> 3;      // local in [0,32)
  const int mm = xcd * 8 + (local >> 2), nn = local & 3;
  const int m0 = mm * 256, n0 = nn * 256;

  const short* Abase = A + (size_t)m0 * 1024;
  const short* Bbase = Bt + (size_t)n0 * 1024;

  const f32x4 z4 = {0.f, 0.f, 0.f, 0.f};
  f32x4 acc[8][4];
#pragma unroll
  for (int i = 0; i < 8; ++i)
#pragma unroll
    for (int j = 0; j < 4; ++j) acc[i][j] = z4;

  stage_half(lds + 0 * 32768 + 0 * 8192, Abase, tid);
  stage_half(lds + 0 * 32768 + 1 * 8192, Abase + 128 * 1024, tid);
  stage_half(lds + 0 * 32768 + 2 * 8192, Bbase, tid);
  stage_half(lds + 0 * 32768 + 3 * 8192, Bbase + 128 * 1024, tid);
  stage_half(lds + 1 * 32768 + 2 * 8192, Bbase + 64, tid);
  stage_half(lds + 1 * 32768 + 3 * 8192, Bbase + 128 * 1024 + 64, tid);
  asm volatile("s_waitcnt vmcnt(4)" ::: "memory");
  __builtin_amdgcn_s_barrier();

  for (int kt = 0; kt < 16; ++kt) {
    const int buf = kt & 1;
    const short* Acur = lds + buf * 32768 + wr * 8192;
    const short* Bcur = lds + buf * 32768 + (2 + (wc >> 1)) * 8192;
    const int brow0 = (wc & 1) * 64;

    bf16x8 bfr[4][2];

    {
#pragma unroll
      for (int j = 0; j < 4; ++j)
#pragma unroll
        for (int ks = 0; ks < 2; ++ks)
          bfr[j][ks] = frag_ld(Bcur, brow0 + j * 16 + l16, ks, q4);
      bf16x8 afr[2][2];
#pragma unroll
      for (int m2 = 0; m2 < 2; ++m2)
#pragma unroll
        for (int ks = 0; ks < 2; ++ks)
          afr[m2][ks] = frag_ld(Acur, m2 * 16 + l16, ks, q4);
      if (kt < 15)
        stage_half(lds + (buf ^ 1) * 32768 + 0 * 8192, Abase + (size_t)(kt + 1) * 64, tid);
      asm volatile("s_waitcnt lgkmcnt(8)" ::: "memory");
      __builtin_amdgcn_s_barrier();
      asm volatile("s_waitcnt lgkmcnt(0)" ::: "memory");
      __builtin_amdgcn_s_setprio(1);
#pragma unroll
      for (int ks = 0; ks < 2; ++ks)
#pragma unroll
        for (int m2 = 0; m2 < 2; ++m2)
#pragma unroll
          for (int j = 0; j < 4; ++j)
            acc[m2][j] = __builtin_amdgcn_mfma_f32_16x16x32_bf16(
                afr[m2][ks], bfr[j][ks], acc[m2][j], 0, 0, 0);
      __builtin_amdgcn_s_setprio(0);
      __builtin_amdgcn_s_barrier();
    }

#pragma unroll
    for (int p = 1; p < 4; ++p) {
      bf16x8 afr[2][2];
#pragma unroll
      for (int m2 = 0; m2 < 2; ++m2)
#pragma unroll
        for (int ks = 0; ks < 2; ++ks)
          afr[m2][ks] = frag_ld(Acur, (p * 2 + m2) * 16 + l16, ks, q4);
      if (p == 1) {
        if (kt < 15)
          stage_half(lds + (buf ^ 1) * 32768 + 1 * 8192,
                     Abase + 128 * 1024 + (size_t)(kt + 1) * 64, tid);
      } else if (p == 2) {
        if (kt < 14)
          stage_half(lds + buf * 32768 + 2 * 8192, Bbase + (size_t)(kt + 2) * 64, tid);
      } else {
        if (kt < 14)
          stage_half(lds + buf * 32768 + 3 * 8192,
                     Bbase + 128 * 1024 + (size_t)(kt + 2) * 64, tid);
      }
      __builtin_amdgcn_s_barrier();
      asm volatile("s_waitcnt lgkmcnt(0)" ::: "memory");
      __builtin_amdgcn_s_setprio(1);
#pragma unroll
      for (int ks = 0; ks < 2; ++ks)
#pragma unroll
        for (int m2 = 0; m2 < 2; ++m2)
#pragma unroll
          for (int j = 0; j < 4; ++j)
            acc[p * 2 + m2][j] = __builtin_amdgcn_mfma_f32_16x16x32_bf16(
                afr[m2][ks], bfr[j][ks], acc[p * 2 + m2][j], 0, 0, 0);
      __builtin_amdgcn_s_setprio(0);
      if (p == 3) {
        if (kt < 14) asm volatile("s_waitcnt vmcnt(4)" ::: "memory");
        else         asm volatile("s_waitcnt vmcnt(0)" ::: "memory");
      }
      __builtin_amdgcn_s_barrier();
    }
  }

#pragma unroll
  for (int m = 0; m < 8; ++m)
#pragma unroll
    for (int j = 0; j < 4; ++j)
#pragma unroll
      for (int rg = 0; rg < 4; ++rg) {
        const int row = m0 + wr * 128 + m * 16 + q4 * 4 + rg;
        const int col = n0 + wc * 64 + j * 16 + l16;
        outf[(size_t)row * 1024 + col] = acc[m][j][rg];
      }
}

// ---------------------------------------------------------------------------
// REL GEMM (counted-vmcnt double-buffer, unchanged).
__global__ __launch_bounds__(256, 2)
void rel_gemm_k(const short* __restrict__ A, const short* __restrict__ Bt,
                short* __restrict__ relk) {
  __shared__ __align__(16) short As[2][128 * 32];
  __shared__ __align__(16) short Bs[2][128 * 32];

  const int tid = threadIdx.x;
  const int lane = tid & 63, wid = tid >> 6;
  const int q4 = lane >> 4, l16 = lane & 15;
  const int wr = wid >> 1, wc = wid & 1;
  const int m0 = blockIdx.x * 128, n0 = blockIdx.y * 128;

  const f32x4 z4 = {0.f, 0.f, 0.f, 0.f};
  f32x4 acc[4][4];
#pragma unroll
  for (int i = 0; i < 4; ++i)
#pragma unroll
    for (int j = 0; j < 4; ++j) acc[i][j] = z4;

  const int r0 = tid >> 2, s0_ = (tid & 3) * 8;

  {
    gl16(&As[0][tid * 8],         A  + (size_t)(m0 + r0) * 1024 + s0_);
    gl16(&Bs[0][tid * 8],         Bt + (size_t)(n0 + r0) * 1024 + s0_);
    gl16(&As[0][(256 + tid) * 8], A  + (size_t)(m0 + 64 + r0) * 1024 + s0_);
    gl16(&Bs[0][(256 + tid) * 8], Bt + (size_t)(n0 + 64 + r0) * 1024 + s0_);
  }

  for (int kt = 0; kt < 32; ++kt) {
    const int buf = kt & 1;
    if (kt < 31) {
      const int kk = (kt + 1) * 32;
      gl16(&As[buf ^ 1][tid * 8],         A  + (size_t)(m0 + r0) * 1024 + kk + s0_);
      gl16(&Bs[buf ^ 1][tid * 8],         Bt + (size_t)(n0 + r0) * 1024 + kk + s0_);
      gl16(&As[buf ^ 1][(256 + tid) * 8], A  + (size_t)(m0 + 64 + r0) * 1024 + kk + s0_);
      gl16(&Bs[buf ^ 1][(256 + tid) * 8], Bt + (size_t)(n0 + 64 + r0) * 1024 + kk + s0_);
      asm volatile("s_waitcnt vmcnt(4)" ::: "memory");
    } else {
      asm volatile("s_waitcnt vmcnt(0)" ::: "memory");
    }
    __builtin_amdgcn_s_barrier();

    bf16x8 af[4], bfv[4];
#pragma unroll
    for (int i = 0; i < 4; ++i)
      af[i] = *(const bf16x8*)&As[buf][(wr * 64 + i * 16 + l16) * 32 + q4 * 8];
#pragma unroll
    for (int j = 0; j < 4; ++j)
      bfv[j] = *(const bf16x8*)&Bs[buf][(wc * 64 + j * 16 + l16) * 32 + q4 * 8];
#pragma unroll
    for (int i = 0; i < 4; ++i)
#pragma unroll
      for (int j = 0; j < 4; ++j)
        acc[i][j] = __builtin_amdgcn_mfma_f32_16x16x32_bf16(af[i], bfv[j], acc[i][j], 0, 0, 0);
    __builtin_amdgcn_s_barrier();
  }

#pragma unroll
  for (int i = 0; i < 4; ++i)
#pragma unroll
    for (int j = 0; j < 4; ++j)
#pragma unroll
      for (int rg = 0; rg < 4; ++rg) {
        const int row = m0 + wr * 64 + i * 16 + q4 * 4 + rg;
        const int col = n0 + wc * 64 + j * 16 + l16;
        int h = col >> 7, d = col & 127;
        relk[(size_t)(h * 384 + row) * 128 + d] = f2bf(acc[i][j][rg]);
      }
}

// ---------------------------------------------------------------------------
// R13 bd GEMM, single-stage + slab XOR-swizzle (slot ^= (row>>1)&3).
__global__ __launch_bounds__(256, 2)
void bd_gemm_k(const short* __restrict__ qb_b, const short* __restrict__ relk,
               short* __restrict__ bds) {
  __shared__ __align__(16) short As[4 * 128 * 32];  // 32 KB
  __shared__ __align__(16) short Bs[4 * 128 * 32];  // 32 KB
  const int tid = threadIdx.x;
  const int lane = tid & 63, wid = tid >> 6;
  const int q4 = lane >> 4, l16 = lane & 15;
  const int wr = wid >> 1, wc = wid & 1;
  const int p0 = blockIdx.x * 128;
  const int nh = blockIdx.y;          // n*8 + h  (within b)
  const int h = nh & 7;
  const short* A = qb_b + (size_t)nh * 16384;
  const short* Bt = relk + (size_t)h * (384 * 128);
  short* bdo = bds + (size_t)nh * 49152;

  // stage full 128x128 tiles, swizzled: LDS[dc][row][slot] = G[row][dc*32 + (slot^xr)*8]
#pragma unroll
  for (int it = 0; it < 8; ++it) {
    int ci = it * 256 + tid;                       // [0,2048)
    int dc = ci >> 9, rr = (ci >> 2) & 127, slot = ci & 3;
    int sub = (slot ^ ((rr >> 1) & 3)) * 8;
    gl16(&As[ci * 8], A + (size_t)rr * 128 + dc * 32 + sub);
  }
#pragma unroll
  for (int it = 0; it < 8; ++it) {
    int ci = it * 256 + tid;
    int dc = ci >> 9, rr = (ci >> 2) & 127, slot = ci & 3;
    int sub = (slot ^ ((rr >> 1) & 3)) * 8;
    gl16(&Bs[ci * 8], Bt + (size_t)(p0 + rr) * 128 + dc * 32 + sub);
  }
  asm volatile("s_waitcnt vmcnt(0)" ::: "memory");
  __builtin_amdgcn_s_barrier();

  const int sx = (l16 >> 1) & 3;       // row>>1 & 3 for rows = base16 + l16
  const f32x4 z4 = {0.f, 0.f, 0.f, 0.f};
  f32x4 acc[4][4];
#pragma unroll
  for (int i = 0; i < 4; ++i)
#pragma unroll
    for (int j = 0; j < 4; ++j) acc[i][j] = z4;

#pragma unroll
  for (int dc = 0; dc < 4; ++dc) {
    bf16x8 af[4], bfv[4];
#pragma unroll
    for (int i = 0; i < 4; ++i)
      af[i] = *(const bf16x8*)&As[dc * 4096 + (wr * 64 + i * 16 + l16) * 32 + (q4 ^ sx) * 8];
#pragma unroll
    for (int j = 0; j < 4; ++j)
      bfv[j] = *(const bf16x8*)&Bs[dc * 4096 + (wc * 64 + j * 16 + l16) * 32 + (q4 ^ sx) * 8];
#pragma unroll
    for (int i = 0; i < 4; ++i)
#pragma unroll
      for (int j = 0; j < 4; ++j)
        acc[i][j] = __builtin_amdgcn_mfma_f32_16x16x32_bf16(af[i], bfv[j], acc[i][j], 0, 0, 0);
  }

  // rel-shift: (r,p) -> (c,k): flat r*384+p == c*383+k, drop c >= 128
#pragma unroll
  for (int i = 0; i < 4; ++i)
#pragma unroll
    for (int j = 0; j < 4; ++j)
#pragma unroll
      for (int rg = 0; rg < 4; ++rg) {
        int r = wr * 64 + i * 16 + q4 * 4 + rg;
        int p = p0 + wc * 64 + j * 16 + l16;
        int t = r + p;
        int c = (t < 383) ? r : (r + 1);
        int k = (t < 383) ? t : (t - 383);
        if (c < 128) {
          int tt = k >> 7, jj = (k >> 4) & 7, ll = k & 15;
          int wa = c >> 5, ia = (c >> 4) & 1, qa = (c >> 2) & 3, ra = c & 3;
          bdo[((((size_t)tt * 8 + jj) * 256) + wa * 64 + qa * 16 + ll) * 8 + ia * 4 + ra] =
              f2bf(acc[i][j][rg]);
        }
      }
}

// ---------------------------------------------------------------------------
// R13 fused local attention: R10 schedule + slab XOR-swizzle on Q/K/V
// (slot ^= (row>>1)&3; linear gl16 dest, inverse-permuted source, swizzled
// reads). b_fixed >= 0: legacy per-b launch (grid 1024). b_fixed < 0: merged
// launch (grid 2048), b derived from blockIdx, bds stride bds_bstride.
__global__ __launch_bounds__(256, 2)
void attn_k(const short* __restrict__ qb_all, const short* __restrict__ kpad,
            const short* __restrict__ vpadT, const short* __restrict__ bds,
            short* __restrict__ attnout, int b_fixed, size_t bds_bstride) {
  __shared__ __align__(16) short Ks[4 * 128 * 32]; // K slabs [dc][key][32], swz
  __shared__ __align__(16) short Vs[4 * 128 * 32]; // V slabs [kc][d][32keys], swz
  __shared__ __align__(16) short Ps[64 * 128];     // Q stage (swz) -> P tile (XOR)

  const int tid = threadIdx.x;
  const int lane = tid & 63, wid = tid >> 6;
  const int q4 = lane >> 4, l16 = lane & 15;
  const int bx = blockIdx.x;
  const int h = bx & 7;               // XCD-pinned head
  const int rest = bx >> 3;
  int b, local;
  if (b_fixed >= 0) { b = b_fixed; local = rest; }
  else              { b = rest >> 7; local = rest & 127; }
  const int n = local >> 1, qh = local & 1;
  const int nh = n * 8 + h;

  const short* qtile = qb_all + (size_t)b * 64 * 8 * 128 * 128 +
                       (size_t)nh * 16384 + qh * 64 * 128;
  const short* kbase = kpad + ((size_t)(b * 8 + h) * 8448 + n * 128) * 128;
  const short* vtb = vpadT + (size_t)(b * 8 + h) * 128 * 8448 + n * 128;
  const short* bdb = bds + (size_t)b * bds_bstride + (size_t)nh * 49152;

  // ---- prologue: Q -> Ps (swz), bd fragments -> regs, K(0) -> Ks (swz)
#pragma unroll
  for (int it = 0; it < 4; ++it) {
    int ci = it * 256 + tid;                     // [0,1024)
    int dc = ci >> 8, rr = (ci >> 2) & 63, slot = ci & 3;
    int sub = (slot ^ ((rr >> 1) & 3)) * 8;
    gl16(&Ps[ci * 8], qtile + rr * 128 + dc * 32 + sub);
  }
  asm volatile("" ::: "memory");       // keep Q gl16 oldest

  // preload ALL bd fragments (3 tiles x 8 j x 8B = 48 VGPRs)
  const int bdoff = ((qh * 2 + (wid >> 1)) * 64 + q4 * 16 + l16) * 8 + (wid & 1) * 4;
  s16x4 bdva[3][8];
#pragma unroll
  for (int t = 0; t < 3; ++t)
#pragma unroll
    for (int j = 0; j < 8; ++j)
      bdva[t][j] = *(const s16x4*)&bdb[(size_t)(t * 8 + j) * 2048 + bdoff];
  asm volatile("" ::: "memory");       // bd loads older than K(0)

#pragma unroll
  for (int it = 0; it < 8; ++it) {
    int ci = it * 256 + tid;
    int dc = ci >> 9, rr = (ci >> 2) & 127, slot = ci & 3;
    int sub = (slot ^ ((rr >> 1) & 3)) * 8;
    gl16(&Ks[ci * 8], kbase + (size_t)rr * 128 + dc * 32 + sub);
  }
  asm volatile("s_waitcnt vmcnt(8)" ::: "memory");  // Q + bd done; K(0) in flight
  asm volatile("s_barrier" ::: "memory");
  const int sx = (l16 >> 1) & 3;                    // read-side slot XOR
  bf16x8 qf[4];
#pragma unroll
  for (int dc = 0; dc < 4; ++dc)
    qf[dc] = *(const bf16x8*)&Ps[dc * 2048 + (wid * 16 + l16) * 32 + (q4 ^ sx) * 8];
  asm volatile("s_waitcnt lgkmcnt(0)" ::: "memory"); // Q reads retired

  const f32x4 z4 = {0.f, 0.f, 0.f, 0.f};
  f32x4 acco[8];
#pragma unroll
  for (int j = 0; j < 8; ++j) acco[j] = z4;
  float rsum[4] = {};

#pragma unroll
  for (int t = 0; t < 3; ++t) {
    asm volatile("s_barrier" ::: "memory");  // (A) Vs/Ps free

    // stage V(t) -> Vs (swz; waited only before PV)
#pragma unroll
    for (int it = 0; it < 8; ++it) {
      int ci = it * 256 + tid;
      int kc = ci >> 9, dd = (ci >> 2) & 127, slot = ci & 3;
      int sub = (slot ^ ((dd >> 1) & 3)) * 8;
      gl16(&Vs[ci * 8], vtb + (size_t)dd * 8448 + t * 128 + kc * 32 + sub);
    }

    asm volatile("s_waitcnt vmcnt(8)" ::: "memory"); // K(t) done, V in flight
    asm volatile("s_barrier" ::: "memory");  // (B) K visible to all waves

    // S = Q @ K^T  (16 rows per wave)
    f32x4 accs[8];
#pragma unroll
    for (int j = 0; j < 8; ++j) accs[j] = z4;
    __builtin_amdgcn_s_setprio(1);
#pragma unroll
    for (int dc = 0; dc < 4; ++dc) {
      bf16x8 kf[8];
#pragma unroll
      for (int j = 0; j < 8; ++j)
        kf[j] = *(const bf16x8*)&Ks[dc * 4096 + (j * 16 + l16) * 32 + (q4 ^ sx) * 8];
#pragma unroll
      for (int j = 0; j < 8; ++j)
        accs[j] = __builtin_amdgcn_mfma_f32_16x16x32_bf16(qf[dc], kf[j], accs[j], 0, 0, 0);
    }
    __builtin_amdgcn_s_setprio(0);

    // logits: s = ac + bd;  w = exp2(-100*log2e / (exp2(s*2*log2e/50) + 1))
#pragma unroll
    for (int j = 0; j < 8; ++j) {
      const int kg = t * 128 + j * 16 + l16;
#pragma unroll
      for (int rg = 0; rg < 4; ++rg) {
        float sv = accs[j][rg] + bf2f((unsigned short)bdva[t][j][rg]);
        float tt = exp2f(sv * 0.057707801635558534f);
        float wgt = exp2f(-144.26950408889634f * __fdividef(1.0f, tt + 1.0f));
        wgt = (kg < 383) ? wgt : 0.0f;
        accs[j][rg] = wgt;
        rsum[rg] += wgt;
      }
    }

    asm volatile("s_barrier" ::: "memory");  // (C) all waves done reading Ks

    // stage K(t+1) -> Ks (swz; overlaps P-write + PV; waited at top of t+1)
    if (t < 2) {
#pragma unroll
      for (int it = 0; it < 8; ++it) {
        int ci = it * 256 + tid;
        int dc = ci >> 9, rr = (ci >> 2) & 127, slot = ci & 3;
        int sub = (slot ^ ((rr >> 1) & 3)) * 8;
        gl16(&Ks[ci * 8], kbase + (size_t)((t + 1) * 128 + rr) * 128 + dc * 32 + sub);
      }
    }

    // write P tile (granule-XOR layout: granule g ^= c&7)
#pragma unroll
    for (int j = 0; j < 8; ++j)
#pragma unroll
      for (int rg = 0; rg < 4; ++rg) {
        int c = wid * 16 + q4 * 4 + rg;
        int kl = j * 16 + l16;
        int g = (kl >> 3) ^ (c & 7);
        Ps[c * 128 + g * 8 + (kl & 7)] = f2bf(accs[j][rg]);
      }

    if (t < 2) asm volatile("s_waitcnt vmcnt(8)" ::: "memory"); // V(t) done, K(t+1) in flight
    else       asm volatile("s_waitcnt vmcnt(0)" ::: "memory"); // final tile: drain
    asm volatile("s_waitcnt lgkmcnt(0)" ::: "memory");          // P writes committed
    asm volatile("s_barrier" ::: "memory");  // (D) V + P ready

    // PV over kc = 0..3
    __builtin_amdgcn_s_setprio(1);
#pragma unroll
    for (int kc = 0; kc < 4; ++kc) {
      int c = wid * 16 + l16;
      int g = (kc * 4 + q4) ^ (c & 7);
      bf16x8 pf = *(const bf16x8*)&Ps[c * 128 + g * 8];
      bf16x8 vf[8];
#pragma unroll
      for (int j = 0; j < 8; ++j)
        vf[j] = *(const bf16x8*)&Vs[kc * 4096 + (j * 16 + l16) * 32 + (q4 ^ sx) * 8];
#pragma unroll
      for (int j = 0; j < 8; ++j)
        acco[j] = __builtin_amdgcn_mfma_f32_16x16x32_bf16(pf, vf[j], acco[j], 0, 0, 0);
    }
    __builtin_amdgcn_s_setprio(0);
  }

  // row-sum butterfly over the 16-lane group (cols), normalize, write bf16
  float rinv[4];
#pragma unroll
  for (int rg = 0; rg < 4; ++rg) {
    float rs = rsum[rg];
    rs += __shfl_xor(rs, 1);
    rs += __shfl_xor(rs, 2);
    rs += __shfl_xor(rs, 4);
    rs += __shfl_xor(rs, 8);
    rinv[rg] = __fdividef(1.0f, rs);
  }
#pragma unroll
  for (int j = 0; j < 8; ++j)
#pragma unroll
    for (int rg = 0; rg < 4; ++rg) {
      int srow = n * 128 + qh * 64 + wid * 16 + q4 * 4 + rg;
      int col = h * 128 + j * 16 + l16;
      attnout[((size_t)b * 8192 + srow) * 1024 + col] = f2bf(acco[j][rg] * rinv[rg]);
    }
}

// ---------------------------------------------------------------------------
extern "C" void kernel_launch(void* const* d_in, const int* in_sizes, int n_in,
                              void* d_out, int out_size, void* d_ws, size_t ws_size,
                              hipStream_t stream) {
  (void)in_sizes; (void)n_in; (void)out_size;
  const float* hs    = (const float*)d_in[0];
  const float* pemb  = (const float*)d_in[1];
  const float* Wq    = (const float*)d_in[2];
  const float* Wk    = (const float*)d_in[3];
  const float* Wv    = (const float*)d_in[4];
  const float* Wrel  = (const float*)d_in[5];
  const float* Wpost = (const float*)d_in[6];
  const float* pds   = (const float*)d_in[7];
  float* out = (float*)d_out;

  char* w = (char*)d_ws;
  auto alloc = [&](size_t bytes) -> char* {
    char* p = w; w += (bytes + 255) & ~(size_t)255; return p;
  };
  short* hs_bf   = (short*)alloc((size_t)16384 * 1024 * 2); // 33.5 MB (attnout aliases later)
  short* pos_bf  = (short*)alloc((size_t)384 * 1024 * 2);
  short* Wq_t    = (short*)alloc((size_t)1024 * 1024 * 2);  // Wq_t..Wpost_t contiguous
  short* Wk_t    = (short*)alloc((size_t)1024 * 1024 * 2);
  short* Wv_t    = (short*)alloc((size_t)1024 * 1024 * 2);
  short* Wrel_t  = (short*)alloc((size_t)1024 * 1024 * 2);
  short* Wpost_t = (short*)alloc((size_t)1024 * 1024 * 2);
  float* qsc     = (float*)alloc(512);
  short* q_bf    = (short*)alloc((size_t)2 * 64 * 8 * 128 * 128 * 2); // 33.5 MB
  short* kpad    = (short*)alloc((size_t)2 * 8 * 8448 * 128 * 2);     // 34.6 MB
  short* vpadT   = (short*)alloc((size_t)2 * 8 * 128 * 8448 * 2);     // 34.6 MB
  short* relk    = (short*)alloc((size_t)8 * 384 * 128 * 2);
  const size_t bds_one = (size_t)64 * 8 * 128 * 384 * 2;              // 50.3 MB
  short* bds     = (short*)alloc(bds_one);
  short* attnout = hs_bf;  // hs_bf dead after QKV projection; attn starts after

  // merged-attn path needs a second bds (counter visibility + fewer gaps)
  const bool merged = ((size_t)(w - (char*)d_ws) + bds_one + 512) <= ws_size;
  short* bdsB = merged ? (short*)alloc(bds_one) : nullptr;

  const float kscale = (float)(log1p(exp(1.0)) / log(2.0));
  const double qsb = (1.0 / sqrt(128.0)) / log(2.0);

  cvt_bf16_k<<<16384, 256, 0, stream>>>(hs, hs_bf, 16384 * 1024);
  cvt_bf16_k<<<384, 256, 0, stream>>>(pemb, pos_bf, 384 * 1024);
  wtrans5_k<<<dim3(16, 16, 5), 256, 0, stream>>>(Wq, Wk, Wv, Wrel, Wpost, Wq_t);
  qscale_k<<<1, 128, 0, stream>>>(pds, qsc, qsb);
  kpadzero_k<<<dim3(256, 16), 128, 0, stream>>>(kpad);
  vpadzero_k<<<2048, 256, 0, stream>>>(vpadT);

  qkv256_k<<<768, 512, 0, stream>>>(hs_bf, Wq_t, q_bf, kpad, vpadT, qsc, kscale);
  rel_gemm_k<<<dim3(3, 8), 256, 0, stream>>>(pos_bf, Wrel_t, relk);

  if (merged) {
    bd_gemm_k<<<dim3(3, 512), 256, 0, stream>>>(q_bf, relk, bds);
    bd_gemm_k<<<dim3(3, 512), 256, 0, stream>>>(
        q_bf + (size_t)64 * 8 * 128 * 128, relk, bdsB);
    attn_k<<<2048, 256, 0, stream>>>(q_bf, kpad, vpadT, bds, attnout,
                                     -1, (size_t)(bdsB - bds));
  } else {
    for (int b = 0; b < 2; ++b) {
      const short* qb_b = q_bf + (size_t)b * 64 * 8 * 128 * 128;
      bd_gemm_k<<<dim3(3, 512), 256, 0, stream>>>(qb_b, relk, bds);
      attn_k<<<1024, 256, 0, stream>>>(q_bf, kpad, vpadT, bds, attnout, b, 0);
    }
  }

  post256_k<<<256, 512, 0, stream>>>(attnout, Wpost_t, out);
}